// Round 6
// baseline (550.047 us; speedup 1.0000x reference)
//
#include <hip/hip_runtime.h>
#include <math.h>

#define BB 64
#define TT 1024
#define DD 32
#define GG 128   // 4*D
#define VOCABN 10000
#define QLEN 100

typedef short short8 __attribute__((ext_vector_type(8)));   // 8 bf16 in 4 VGPRs
typedef float floatx4 __attribute__((ext_vector_type(4)));
typedef float floatx2 __attribute__((ext_vector_type(2)));
typedef unsigned short u16;

__device__ __forceinline__ float fsig(float x) {
    return __builtin_amdgcn_rcpf(1.0f + __expf(-x));
}
__device__ __forceinline__ float readlane_f(float v, int l) {
    return __int_as_float(__builtin_amdgcn_readlane(__float_as_int(v), l));
}
__device__ __forceinline__ u16 f2bf_rne(float x) {
    unsigned u = __float_as_uint(x);
    u += 0x7FFF + ((u >> 16) & 1);
    return (u16)(u >> 16);
}
__device__ __forceinline__ float bf2f(u16 s) {
    return __uint_as_float(((unsigned)s) << 16);
}
// packed fma: one v_pk_fma_f32 for the {a,b}-gate pair. IEEE fma per half ->
// bit-exact vs two fmaf.
__device__ __forceinline__ floatx2 fma2(float s, floatx2 w, floatx2 acc) {
    return __builtin_elementwise_fma((floatx2){s, s}, w, acc);
}

// ---------------------------------------------------------------------------
// Kernel 1: LSTM scan — R23: 4 batches/block, 8 waves. Consumers are waves
// 0..3 -> SIMDs 0..3; producers waves 4..7 -> SIMDs 0..3 (round-robin), so
// every SIMD hosts {1 consumer + 1 producer}: the producer's ~1600 issue
// cyc/chunk fills the consumer's ~2900 stall cyc/chunk at the HW scheduler
// level (in-wave filling failed: R17 +39us, R20 +65us; cross-wave per-step
// barriers failed: R18). Per-batch math identical to R21 (measured, absmax
// 0.0): pk_fma dots + permlane32_swap + producer-side cvt.
// Queue fused as block 16 wave 0, unchanged.
// ---------------------------------------------------------------------------
#define UU 8
__global__
__attribute__((amdgpu_flat_work_group_size(512, 512)))
void k_lstm_scan(const int* __restrict__ ids,
                 const float* __restrict__ emb,
                 const float* __restrict__ klstm,
                 const float* __restrict__ bias,
                 const float* __restrict__ rk,
                 float* __restrict__ hout,
                 u16* __restrict__ hh, u16* __restrict__ hl,
                 u16* __restrict__ th, u16* __restrict__ tl,
                 int* __restrict__ list,
                 float* __restrict__ outq) {
    const int blk = blockIdx.x;
    const int tid = threadIdx.x;
    const int wv = tid >> 6;   // 0..3 consumers, 4..7 producers
    const int l = tid & 63;
    if (blk >= BB / 4) {
        if (wv != 0) return;
        // ---- fused zero-index queue (single wave, no barriers) ----
        const int4* v4 = (const int4*)ids;
        const int C4 = (BB * TT) / 4 / 64;
        const int b4 = l * C4;
        int cnt = 0;
#pragma unroll 4
        for (int i = 0; i < C4; ++i) {
            int4 v = v4[b4 + i];
            cnt += (v.x == 0 || (unsigned)v.x >= VOCABN);
            cnt += (v.y == 0 || (unsigned)v.y >= VOCABN);
            cnt += (v.z == 0 || (unsigned)v.z >= VOCABN);
            cnt += (v.w == 0 || (unsigned)v.w >= VOCABN);
        }
        int scan = cnt;
#pragma unroll
        for (int o = 1; o < 64; o <<= 1) {
            int nn = __shfl_up(scan, o);
            if (l >= o) scan += nn;
        }
        const int total = __shfl(scan, 63);
        int off = scan - cnt;
        const int base = l * (C4 * 4);
#pragma unroll 4
        for (int i = 0; i < C4; ++i) {
            int4 v = v4[b4 + i];
            if (v.x == 0 || (unsigned)v.x >= VOCABN) list[off++] = base + 4 * i;
            if (v.y == 0 || (unsigned)v.y >= VOCABN) list[off++] = base + 4 * i + 1;
            if (v.z == 0 || (unsigned)v.z >= VOCABN) list[off++] = base + 4 * i + 2;
            if (v.w == 0 || (unsigned)v.w >= VOCABN) list[off++] = base + 4 * i + 3;
        }
        __threadfence();
        const int Kc = total < QLEN ? total : QLEN;
        for (int t = l; t < QLEN; t += 64) {
            float ii = -1.0f, jj = -1.0f;
            if (t >= QLEN - Kc) {
                int pos = list[total - QLEN + t];
                ii = (float)(pos >> 10);
                jj = (float)(pos & (TT - 1));
            }
            outq[2 * t] = ii;
            outq[2 * t + 1] = jj;
        }
        return;
    }

    const int p = wv & 3;            // pair id = batch slot
    const int b = blk * 4 + p;
    __shared__ float ring[4][2][UU][GG];                 // 32 KB xg rings
    __shared__ __align__(16) float hring[4][2][UU][DD];  // 8 KB h rings
    const int* idsb = ids + b * TT;

    if (wv >= 4) {
        // ---------- producer: xg 8 tokens ahead + cvt of chunk-1 -----------
        const int ja = l, jb = l + 64;
        floatx2 kp[DD];
#pragma unroll
        for (int d2 = 0; d2 < DD; ++d2)
            kp[d2] = (floatx2){klstm[d2 * GG + ja], klstm[d2 * GG + jb]};
        const floatx2 bj = (floatx2){bias[ja], bias[jb]};
        const int dd = l & 31;
        // cvt lane mappings
        const int u_r = l >> 3, dc = (l & 7) * 4;        // row side: 8B u16 runs
        const int d_c = l & 31, ug = (l >> 5) * 4;       // col side: 4 consecutive t
        u16* hhb = hh + (size_t)b * TT * DD;
        u16* hlb = hl + (size_t)b * TT * DD;
        u16* thb = th + (size_t)b * DD * TT;
        u16* tlb = tl + (size_t)b * DD * TT;

#define PROD_TOKEN(SEL, U, EV)                                               \
        {                                                                    \
            floatx2 z0 = bj;                                                 \
            floatx2 z1 = {0.f, 0.f}, z2 = {0.f, 0.f}, z3 = {0.f, 0.f};       \
            _Pragma("unroll")                                                \
            for (int k = 0; k < DD; k += 4) {                                \
                float e0 = readlane_f(EV, k);                                \
                float e1 = readlane_f(EV, k + 1);                            \
                float e2 = readlane_f(EV, k + 2);                            \
                float e3 = readlane_f(EV, k + 3);                            \
                z0 = fma2(e0, kp[k], z0);                                    \
                z1 = fma2(e1, kp[k + 1], z1);                                \
                z2 = fma2(e2, kp[k + 2], z2);                                \
                z3 = fma2(e3, kp[k + 3], z3);                                \
            }                                                                \
            floatx2 zf = (z0 + z1) + (z2 + z3);                              \
            ring[p][SEL][U][ja] = zf.x;                                      \
            ring[p][SEL][U][jb] = zf.y;                                      \
        }

        // convert chunk starting at token TC0 from hring[p][HSEL]
#define CVT_CHUNK(HSEL, TC0)                                                 \
        {                                                                    \
            const float4 hv4 = *(const float4*)&hring[p][HSEL][u_r][dc];     \
            float xr[4] = {hv4.x, hv4.y, hv4.z, hv4.w};                      \
            u16 rh[4], rl[4];                                                \
            _Pragma("unroll")                                                \
            for (int i = 0; i < 4; ++i) {                                    \
                rh[i] = f2bf_rne(xr[i]);                                     \
                rl[i] = f2bf_rne(xr[i] - bf2f(rh[i]));                       \
            }                                                                \
            ushort4 rhv = {rh[0], rh[1], rh[2], rh[3]};                      \
            ushort4 rlv = {rl[0], rl[1], rl[2], rl[3]};                      \
            *(ushort4*)&hhb[(size_t)((TC0) + u_r) * DD + dc] = rhv;          \
            *(ushort4*)&hlb[(size_t)((TC0) + u_r) * DD + dc] = rlv;          \
            u16 ch[4], cl[4];                                                \
            _Pragma("unroll")                                                \
            for (int j = 0; j < 4; ++j) {                                    \
                float x = hring[p][HSEL][ug + j][d_c];                       \
                ch[j] = f2bf_rne(x);                                         \
                cl[j] = f2bf_rne(x - bf2f(ch[j]));                           \
            }                                                                \
            ushort4 chv = {ch[0], ch[1], ch[2], ch[3]};                      \
            ushort4 clv = {cl[0], cl[1], cl[2], cl[3]};                      \
            *(ushort4*)&thb[(size_t)d_c * TT + (TC0) + ug] = chv;            \
            *(ushort4*)&tlb[(size_t)d_c * TT + (TC0) + ug] = clv;            \
        }

        {
            int id0 = idsb[0]; if ((unsigned)id0 >= VOCABN) id0 = 0;
            float ec = emb[id0 * DD + dd];
#pragma unroll
            for (int u = 0; u < UU; ++u) {
                float en = 0.f;
                if (u + 1 < UU) {
                    int idn = idsb[u + 1]; if ((unsigned)idn >= VOCABN) idn = 0;
                    en = emb[idn * DD + dd];
                }
                PROD_TOKEN(0, u, ec)
                ec = en;
            }
        }
        __syncthreads();
        int sel = 0;
        for (int t0 = 0; t0 < TT; t0 += UU) {
            if (t0 + UU < TT) {
                const int s = sel ^ 1;
                int id0 = idsb[t0 + UU]; if ((unsigned)id0 >= VOCABN) id0 = 0;
                float ec = emb[id0 * DD + dd];
#pragma unroll
                for (int u = 0; u < UU; ++u) {
                    float en = 0.f;
                    if (u + 1 < UU) {
                        int tn = t0 + UU + u + 1;
                        if (tn > TT - 1) tn = TT - 1;
                        int idn = idsb[tn]; if ((unsigned)idn >= VOCABN) idn = 0;
                        en = emb[idn * DD + dd];
                    }
                    PROD_TOKEN(s, u, ec)
                    ec = en;
                }
            }
            // cvt previous chunk (consumer wrote hring[p][(t0/UU-1)&1] before
            // the last barrier)
            if (t0) CVT_CHUNK((t0 / UU - 1) & 1, t0 - UU)
            __syncthreads();
            sel ^= 1;
        }
        // epilogue: convert the final chunk (written before the last barrier)
        CVT_CHUNK(1, TT - UU)
#undef PROD_TOKEN
#undef CVT_CHUNK
        return;
    }

    // ---------------- consumer: R21-exact scan + pk_fma dots ----------------
    const int d = l & 31;
    const bool hi = l >= 32;
    const int ga = (hi ? 32 : 0) + d;
    const int gb = (hi ? 96 : 64) + d;
    floatx2 rkp[DD];
#pragma unroll
    for (int k = 0; k < DD; ++k)
        rkp[k] = (floatx2){rk[k * GG + ga], rk[k * GG + gb]};
    float* hb = hout + (size_t)b * TT * DD;

    float h = 0.0f, c = 0.0f;
    float hreg[UU];
    __syncthreads();   // matches producer prologue barrier
    int sel = 0;
    for (int t0 = 0; t0 < TT; t0 += UU) {
        // flush previous chunk's h first: stores retire under this chunk's
        // compute, so the chunk-end barrier's vmcnt(0) drain is free.
        if (t0 && !hi) {
#pragma unroll
            for (int u = 0; u < UU; ++u) hb[(size_t)(t0 - UU + u) * DD + d] = hreg[u];
        }
        float pa[UU], pb[UU];
#pragma unroll
        for (int u = 0; u < UU; ++u) {
            pa[u] = ring[p][sel][u][ga];
            pb[u] = ring[p][sel][u][gb];
        }
#pragma unroll
        for (int u = 0; u < UU; ++u) {
            floatx2 x0 = {pa[u], pb[u]};
            floatx2 x1 = {0.f, 0.f}, x2 = {0.f, 0.f}, x3 = {0.f, 0.f};
#pragma unroll
            for (int k = 0; k < DD; k += 4) {
                float h0 = readlane_f(h, k);
                float h1 = readlane_f(h, k + 1);
                float h2 = readlane_f(h, k + 2);
                float h3 = readlane_f(h, k + 3);
                x0 = fma2(h0, rkp[k],     x0);
                x1 = fma2(h1, rkp[k + 1], x1);
                x2 = fma2(h2, rkp[k + 2], x2);
                x3 = fma2(h3, rkp[k + 3], x3);
            }
            floatx2 zf = (x0 + x1) + (x2 + x3);
            float za = zf.x, zb = zf.y;
            float a = fsig(za);                       // sig(i) lo / sig(f) hi
            float zbm = hi ? zb : 2.0f * zb;
            float s2 = fsig(zbm);
            float bv = hi ? s2 : 2.0f * s2 - 1.0f;    // sig(o) hi / tanh(g) lo
            // lane<32 <-> lane+32 exchange via v_permlane32_swap_b32 (VALU).
            auto r1 = __builtin_amdgcn_permlane32_swap(
                __float_as_int(bv), __float_as_int(a), false, false);
            auto r2 = __builtin_amdgcn_permlane32_swap(
                __float_as_int(a), __float_as_int(bv), false, false);
            float fg = __int_as_float(r1[0]);
            float og = __int_as_float(r2[0]);
            c = fmaf(fg, c, a * bv);
            float tc = 2.0f * fsig(2.0f * c) - 1.0f;
            h = og * tc;
            hreg[u] = h;
            if (!hi) hring[p][sel][u][d] = h;   // h ring for producer-side cvt
        }
        __syncthreads();
        sel ^= 1;
    }
    if (!hi) {
#pragma unroll
        for (int u = 0; u < UU; ++u) hb[(size_t)(TT - UU + u) * DD + d] = hreg[u];
    }
}

// ---------------------------------------------------------------------------
// Kernel 3: attention — R22 version (2 q-tiles/wave), unchanged.
// ---------------------------------------------------------------------------
__global__ __launch_bounds__(256, 2) void k_attn(const u16* __restrict__ hh,
                                                 const u16* __restrict__ hl,
                                                 const u16* __restrict__ th,
                                                 const u16* __restrict__ tl,
                                                 float* __restrict__ ctx) {
    __shared__ u16 plds[4][2][2][16 * 40];   // [wave][tile][dbuf][16x40]
    const int tid = threadIdx.x;
    const int w = tid >> 6;
    const int l = tid & 63;
    const int m = l & 15;
    const int g = l >> 4;
    const int b = blockIdx.x & 63;              // XCD swizzle: XCD = b % 8
    const int qt = (blockIdx.x >> 6) * 4 + w;   // 32-row wave tile, 0..31
    const int q0 = qt * 32;
    const size_t rb = (size_t)b * TT * DD;
    const size_t tb = (size_t)b * DD * TT;

    const short8 Qh0 = *(const short8*)&hh[rb + (size_t)(q0 + m) * DD + g * 8];
    const short8 Ql0 = *(const short8*)&hl[rb + (size_t)(q0 + m) * DD + g * 8];
    const short8 Qh1 = *(const short8*)&hh[rb + (size_t)(q0 + 16 + m) * DD + g * 8];
    const short8 Ql1 = *(const short8*)&hl[rb + (size_t)(q0 + 16 + m) * DD + g * 8];
    short8 ONES;
#pragma unroll
    for (int j = 0; j < 8; ++j) ONES[j] = (short)0x3F80;

    floatx4 c0 = {0.f, 0.f, 0.f, 0.f};   // tile0 cols 0-15
    floatx4 c1 = {0.f, 0.f, 0.f, 0.f};   // tile0 cols 16-31
    floatx4 c2 = {0.f, 0.f, 0.f, 0.f};   // tile1 cols 0-15
    floatx4 c3 = {0.f, 0.f, 0.f, 0.f};   // tile1 cols 16-31
    floatx4 la0 = {0.f, 0.f, 0.f, 0.f};
    floatx4 la1 = {0.f, 0.f, 0.f, 0.f};

#define S_BLOCK(QH, QL, KH_A, KL_A, KH_B, KL_B, SA, SB)                       \
    SA = __builtin_amdgcn_mfma_f32_16x16x32_bf16(QH, KH_A, SA, 0, 0, 0);      \
    SA = __builtin_amdgcn_mfma_f32_16x16x32_bf16(QH, KL_A, SA, 0, 0, 0);      \
    SA = __builtin_amdgcn_mfma_f32_16x16x32_bf16(QL, KH_A, SA, 0, 0, 0);      \
    SB = __builtin_amdgcn_mfma_f32_16x16x32_bf16(QH, KH_B, SB, 0, 0, 0);      \
    SB = __builtin_amdgcn_mfma_f32_16x16x32_bf16(QH, KL_B, SB, 0, 0, 0);      \
    SB = __builtin_amdgcn_mfma_f32_16x16x32_bf16(QL, KH_B, SB, 0, 0, 0);

    // ---- kp = 0: S + exp + write slot0 for BOTH tiles; no PV yet ----
    {
        short8 KhA = *(const short8*)&hh[rb + (size_t)(m) * DD + g * 8];
        short8 KlA = *(const short8*)&hl[rb + (size_t)(m) * DD + g * 8];
        short8 KhB = *(const short8*)&hh[rb + (size_t)(16 + m) * DD + g * 8];
        short8 KlB = *(const short8*)&hl[rb + (size_t)(16 + m) * DD + g * 8];
        floatx4 sA = {0.f, 0.f, 0.f, 0.f};
        floatx4 sB = {0.f, 0.f, 0.f, 0.f};
        floatx4 tA = {0.f, 0.f, 0.f, 0.f};
        floatx4 tB = {0.f, 0.f, 0.f, 0.f};
        S_BLOCK(Qh0, Ql0, KhA, KlA, KhB, KlB, sA, sB)
        S_BLOCK(Qh1, Ql1, KhA, KlA, KhB, KlB, tA, tB)
        u16* p0 = plds[w][0][0];
        u16* p1 = plds[w][1][0];
#pragma unroll
        for (int r = 0; r < 4; ++r) {
            p0[(g * 4 + r) * 40 + m]      = f2bf_rne(__expf(sA[r]));
            p0[(g * 4 + r) * 40 + 16 + m] = f2bf_rne(__expf(sB[r]));
            p1[(g * 4 + r) * 40 + m]      = f2bf_rne(__expf(tA[r]));
            p1[(g * 4 + r) * 40 + 16 + m] = f2bf_rne(__expf(tB[r]));
        }
    }
    // preload V_0 (used at kp=1) and K_1 — shared by both tiles
    short8 Vh0 = *(const short8*)&th[tb + (size_t)m * TT + g * 8];
    short8 Vl0 = *(const short8*)&tl[tb + (size_t)m * TT + g * 8];
    short8 Vh1 = *(const short8*)&th[tb + (size_t)(16 + m) * TT + g * 8];
    short8 Vl1 = *(const short8*)&tl[tb + (size_t)(16 + m) * TT + g * 8];
    short8 KhA = *(const short8*)&hh[rb + (size_t)(32 + m) * DD + g * 8];
    short8 KlA = *(const short8*)&hl[rb + (size_t)(32 + m) * DD + g * 8];
    short8 KhB = *(const short8*)&hh[rb + (size_t)(48 + m) * DD + g * 8];
    short8 KlB = *(const short8*)&hl[rb + (size_t)(48 + m) * DD + g * 8];

#pragma unroll 1
    for (int kp = 1; kp < 32; ++kp) {
        const int knK = (kp < 31) ? (kp + 1) * 32 : 0;
        const int knV = kp * 32;
        short8 nKhA = *(const short8*)&hh[rb + (size_t)(knK + m) * DD + g * 8];
        short8 nKlA = *(const short8*)&hl[rb + (size_t)(knK + m) * DD + g * 8];
        short8 nKhB = *(const short8*)&hh[rb + (size_t)(knK + 16 + m) * DD + g * 8];
        short8 nKlB = *(const short8*)&hl[rb + (size_t)(knK + 16 + m) * DD + g * 8];
        short8 nVh0 = *(const short8*)&th[tb + (size_t)m * TT + knV + g * 8];
        short8 nVl0 = *(const short8*)&tl[tb + (size_t)m * TT + knV + g * 8];
        short8 nVh1 = *(const short8*)&th[tb + (size_t)(16 + m) * TT + knV + g * 8];
        short8 nVl1 = *(const short8*)&tl[tb + (size_t)(16 + m) * TT + knV + g * 8];

        floatx4 sA = {0.f, 0.f, 0.f, 0.f};
        floatx4 sB = {0.f, 0.f, 0.f, 0.f};
        floatx4 tA = {0.f, 0.f, 0.f, 0.f};
        floatx4 tB = {0.f, 0.f, 0.f, 0.f};
        S_BLOCK(Qh0, Ql0, KhA, KlA, KhB, KlB, sA, sB)
        S_BLOCK(Qh1, Ql1, KhA, KlA, KhB, KlB, tA, tB)

        const short8 P0 = *(const short8*)&plds[w][0][(kp - 1) & 1][m * 40 + g * 8];
        const short8 P1 = *(const short8*)&plds[w][1][(kp - 1) & 1][m * 40 + g * 8];

        u16 pe0[8], pe1[8];
#pragma unroll
        for (int r = 0; r < 4; ++r) {
            pe0[r]     = f2bf_rne(__expf(sA[r]));
            pe0[4 + r] = f2bf_rne(__expf(sB[r]));
            pe1[r]     = f2bf_rne(__expf(tA[r]));
            pe1[4 + r] = f2bf_rne(__expf(tB[r]));
        }

        c0  = __builtin_amdgcn_mfma_f32_16x16x32_bf16(P0, Vh0, c0, 0, 0, 0);
        c0  = __builtin_amdgcn_mfma_f32_16x16x32_bf16(P0, Vl0, c0, 0, 0, 0);
        c1  = __builtin_amdgcn_mfma_f32_16x16x32_bf16(P0, Vh1, c1, 0, 0, 0);
        c1  = __builtin_amdgcn_mfma_f32_16x16x32_bf16(P0, Vl1, c1, 0, 0, 0);
        la0 = __builtin_amdgcn_mfma_f32_16x16x32_bf16(P0, ONES, la0, 0, 0, 0);
        c2  = __builtin_amdgcn_mfma_f32_16x16x32_bf16(P1, Vh0, c2, 0, 0, 0);
        c2  = __builtin_amdgcn_mfma_f32_16x16x32_bf16(P1, Vl0, c2, 0, 0, 0);
        c3  = __builtin_amdgcn_mfma_f32_16x16x32_bf16(P1, Vh1, c3, 0, 0, 0);
        c3  = __builtin_amdgcn_mfma_f32_16x16x32_bf16(P1, Vl1, c3, 0, 0, 0);
        la1 = __builtin_amdgcn_mfma_f32_16x16x32_bf16(P1, ONES, la1, 0, 0, 0);

        u16* w0 = plds[w][0][kp & 1];
        u16* w1 = plds[w][1][kp & 1];
#pragma unroll
        for (int r = 0; r < 4; ++r) {
            w0[(g * 4 + r) * 40 + m]      = pe0[r];
            w0[(g * 4 + r) * 40 + 16 + m] = pe0[4 + r];
            w1[(g * 4 + r) * 40 + m]      = pe1[r];
            w1[(g * 4 + r) * 40 + 16 + m] = pe1[4 + r];
        }

        KhA = nKhA; KlA = nKlA; KhB = nKhB; KlB = nKlB;
        Vh0 = nVh0; Vl0 = nVl0; Vh1 = nVh1; Vl1 = nVl1;
    }
    // epilogue: PV of kp=31 for both tiles
    {
        const short8 P0 = *(const short8*)&plds[w][0][31 & 1][m * 40 + g * 8];
        const short8 P1 = *(const short8*)&plds[w][1][31 & 1][m * 40 + g * 8];
        c0  = __builtin_amdgcn_mfma_f32_16x16x32_bf16(P0, Vh0, c0, 0, 0, 0);
        c0  = __builtin_amdgcn_mfma_f32_16x16x32_bf16(P0, Vl0, c0, 0, 0, 0);
        c1  = __builtin_amdgcn_mfma_f32_16x16x32_bf16(P0, Vh1, c1, 0, 0, 0);
        c1  = __builtin_amdgcn_mfma_f32_16x16x32_bf16(P0, Vl1, c1, 0, 0, 0);
        la0 = __builtin_amdgcn_mfma_f32_16x16x32_bf16(P0, ONES, la0, 0, 0, 0);
        c2  = __builtin_amdgcn_mfma_f32_16x16x32_bf16(P1, Vh0, c2, 0, 0, 0);
        c2  = __builtin_amdgcn_mfma_f32_16x16x32_bf16(P1, Vl0, c2, 0, 0, 0);
        c3  = __builtin_amdgcn_mfma_f32_16x16x32_bf16(P1, Vh1, c3, 0, 0, 0);
        c3  = __builtin_amdgcn_mfma_f32_16x16x32_bf16(P1, Vl1, c3, 0, 0, 0);
        la1 = __builtin_amdgcn_mfma_f32_16x16x32_bf16(P1, ONES, la1, 0, 0, 0);
    }
#undef S_BLOCK
#pragma unroll
    for (int r = 0; r < 4; ++r) {
        float li0 = __builtin_amdgcn_rcpf(la0[r]);
        float li1 = __builtin_amdgcn_rcpf(la1[r]);
        float* cr0 = ctx + (size_t)b * TT * DD + (size_t)(q0 + g * 4 + r) * DD;
        float* cr1 = ctx + (size_t)b * TT * DD + (size_t)(q0 + 16 + g * 4 + r) * DD;
        cr0[m]      = c0[r] * li0;
        cr0[16 + m] = c1[r] * li0;
        cr1[m]      = c2[r] * li1;
        cr1[16 + m] = c3[r] * li1;
    }
}

// ---------------------------------------------------------------------------
// Kernel 4: ymlp — R13 version, unchanged.
// ---------------------------------------------------------------------------
__global__ __launch_bounds__(256) void k_ymlp(const float* __restrict__ ctx,
                                              const float* __restrict__ h,
                                              const float* __restrict__ W1,
                                              const float* __restrict__ b1,
                                              const float* __restrict__ W2,
                                              const float* __restrict__ b2,
                                              float* __restrict__ out) {
    const int b = blockIdx.x;
    const int tid = threadIdx.x;
    __shared__ __align__(16) float cs[128 * DD];
    __shared__ __align__(16) float hs[128 * DD];
    const float* cb = ctx + (size_t)b * TT * DD;
    const float* hb = h + (size_t)b * TT * DD;
    const int e = tid & 31;
    const int d4 = (tid >> 5) * 4;
    float acc[4] = {0.f, 0.f, 0.f, 0.f};
    for (int kt = 0; kt < 8; ++kt) {
        const float4* s1 = (const float4*)(cb + (size_t)kt * 128 * DD);
        const float4* s2 = (const float4*)(hb + (size_t)kt * 128 * DD);
        float4* t1 = (float4*)cs;
        float4* t2 = (float4*)hs;
#pragma unroll
        for (int n = 0; n < 4; ++n) {
            t1[tid + n * 256] = s1[tid + n * 256];
            t2[tid + n * 256] = s2[tid + n * 256];
        }
        __syncthreads();
#pragma unroll 2
        for (int s = 0; s < 128; ++s) {
            float hv = hs[s * DD + e];
            float4 cv = *(const float4*)&cs[s * DD + d4];
            acc[0] = fmaf(cv.x, hv, acc[0]);
            acc[1] = fmaf(cv.y, hv, acc[1]);
            acc[2] = fmaf(cv.z, hv, acc[2]);
            acc[3] = fmaf(cv.w, hv, acc[3]);
        }
        __syncthreads();
    }
    __shared__ float ys[DD][DD];
#pragma unroll
    for (int r = 0; r < 4; ++r) ys[d4 + r][e] = acc[r];
    __syncthreads();
    __shared__ float yr[DD][33];
#pragma unroll
    for (int r = 0; r < 4; ++r) {
        float v = b1[e];
#pragma unroll
        for (int ee = 0; ee < DD; ++ee) v += ys[d4 + r][ee] * W1[ee * DD + e];
        yr[d4 + r][e] = fmaxf(v, 0.0f);
    }
    __syncthreads();
    if (tid < DD) {
        float v = b2[0];
#pragma unroll
        for (int ee = 0; ee < DD; ++ee) v += yr[tid][ee] * W2[ee];
        out[b * DD + tid] = 1.0f / (1.0f + expf(-v));
    }
}

// ---------------------------------------------------------------------------
extern "C" void kernel_launch(void* const* d_in, const int* in_sizes, int n_in,
                              void* d_out, int out_size, void* d_ws, size_t ws_size,
                              hipStream_t stream) {
    const int* ids   = (const int*)d_in[0];
    const float* emb = (const float*)d_in[1];
    const float* kl  = (const float*)d_in[2];
    const float* rk  = (const float*)d_in[3];
    const float* bl  = (const float*)d_in[4];
    const float* W1  = (const float*)d_in[5];
    const float* b1  = (const float*)d_in[6];
    const float* W2  = (const float*)d_in[7];
    const float* b2  = (const float*)d_in[8];
    float* out = (float*)d_out;

    char* ws = (char*)d_ws;
    const size_t H_ELEMS = (size_t)BB * TT * DD;   // 2,097,152
    u16* hh   = (u16*)ws;
    u16* hl   = (u16*)(ws + H_ELEMS * 2);
    u16* th   = (u16*)(ws + H_ELEMS * 4);
    u16* tl   = (u16*)(ws + H_ELEMS * 6);
    float* h  = (float*)(ws + H_ELEMS * 8);
    float* ctx = (float*)(ws + H_ELEMS * 8 + H_ELEMS * 4);
    int* list = (int*)(ws + H_ELEMS * 8 + H_ELEMS * 8);

    k_lstm_scan<<<BB / 4 + 1, 512, 0, stream>>>(ids, emb, kl, bl, rk, h,
                                                hh, hl, th, tl, list, out + BB * DD);
    k_attn<<<BB * 8, 256, 0, stream>>>(hh, hl, th, tl, ctx);
    k_ymlp<<<BB, 256, 0, stream>>>(ctx, h, W1, b1, W2, b2, out);
}

// Round 7
// 543.709 us; speedup vs baseline: 1.0117x; 1.0117x over previous
//
#include <hip/hip_runtime.h>
#include <math.h>

#define BB 64
#define TT 1024
#define DD 32
#define GG 128   // 4*D
#define VOCABN 10000
#define QLEN 100

typedef short short8 __attribute__((ext_vector_type(8)));   // 8 bf16 in 4 VGPRs
typedef float floatx4 __attribute__((ext_vector_type(4)));
typedef float floatx2 __attribute__((ext_vector_type(2)));
typedef unsigned short u16;

__device__ __forceinline__ float fsig(float x) {
    return __builtin_amdgcn_rcpf(1.0f + __expf(-x));
}
__device__ __forceinline__ float readlane_f(float v, int l) {
    return __int_as_float(__builtin_amdgcn_readlane(__float_as_int(v), l));
}
__device__ __forceinline__ u16 f2bf_rne(float x) {
    unsigned u = __float_as_uint(x);
    u += 0x7FFF + ((u >> 16) & 1);
    return (u16)(u >> 16);
}
__device__ __forceinline__ float bf2f(u16 s) {
    return __uint_as_float(((unsigned)s) << 16);
}
// packed fma: one v_pk_fma_f32 for the {a,b}-gate pair. IEEE fma per half ->
// bit-exact vs two fmaf.
__device__ __forceinline__ floatx2 fma2(float s, floatx2 w, floatx2 acc) {
    return __builtin_elementwise_fma((floatx2){s, s}, w, acc);
}

// ---------------------------------------------------------------------------
// Kernel 1: LSTM scan — R24 = R23 retried with the register allocator PINNED.
// R23 post-mortem: VGPR_Count 132->60 — without waves_per_eu the compiler
// targeted high occupancy and SPILLED the 64-VGPR weight arrays to scratch
// (258->398 µs). The co-residency experiment was confounded, not falsified.
// waves_per_eu(2,2): min 2 waves/EU caps VGPR at 256 (we need ~132) and is
// exactly the intended {1 consumer + 1 producer} per SIMD.
// 4 batches/block, 8 waves: consumers wv0..3 -> SIMD0..3, producers wv4..7
// -> SIMD0..3; producer issue (~1600 cyc/chunk) fills consumer stalls
// (~2900 cyc/chunk) at the HW scheduler level. Per-batch math identical to
// R21 (absmax 0.0): pk_fma dots + permlane32_swap + producer-side cvt.
// ---------------------------------------------------------------------------
#define UU 8
__global__
__attribute__((amdgpu_flat_work_group_size(512, 512)))
__attribute__((amdgpu_waves_per_eu(2, 2)))
void k_lstm_scan(const int* __restrict__ ids,
                 const float* __restrict__ emb,
                 const float* __restrict__ klstm,
                 const float* __restrict__ bias,
                 const float* __restrict__ rk,
                 float* __restrict__ hout,
                 u16* __restrict__ hh, u16* __restrict__ hl,
                 u16* __restrict__ th, u16* __restrict__ tl,
                 int* __restrict__ list,
                 float* __restrict__ outq) {
    const int blk = blockIdx.x;
    const int tid = threadIdx.x;
    const int wv = tid >> 6;   // 0..3 consumers, 4..7 producers
    const int l = tid & 63;
    if (blk >= BB / 4) {
        if (wv != 0) return;
        // ---- fused zero-index queue (single wave, no barriers) ----
        const int4* v4 = (const int4*)ids;
        const int C4 = (BB * TT) / 4 / 64;
        const int b4 = l * C4;
        int cnt = 0;
#pragma unroll 4
        for (int i = 0; i < C4; ++i) {
            int4 v = v4[b4 + i];
            cnt += (v.x == 0 || (unsigned)v.x >= VOCABN);
            cnt += (v.y == 0 || (unsigned)v.y >= VOCABN);
            cnt += (v.z == 0 || (unsigned)v.z >= VOCABN);
            cnt += (v.w == 0 || (unsigned)v.w >= VOCABN);
        }
        int scan = cnt;
#pragma unroll
        for (int o = 1; o < 64; o <<= 1) {
            int nn = __shfl_up(scan, o);
            if (l >= o) scan += nn;
        }
        const int total = __shfl(scan, 63);
        int off = scan - cnt;
        const int base = l * (C4 * 4);
#pragma unroll 4
        for (int i = 0; i < C4; ++i) {
            int4 v = v4[b4 + i];
            if (v.x == 0 || (unsigned)v.x >= VOCABN) list[off++] = base + 4 * i;
            if (v.y == 0 || (unsigned)v.y >= VOCABN) list[off++] = base + 4 * i + 1;
            if (v.z == 0 || (unsigned)v.z >= VOCABN) list[off++] = base + 4 * i + 2;
            if (v.w == 0 || (unsigned)v.w >= VOCABN) list[off++] = base + 4 * i + 3;
        }
        __threadfence();
        const int Kc = total < QLEN ? total : QLEN;
        for (int t = l; t < QLEN; t += 64) {
            float ii = -1.0f, jj = -1.0f;
            if (t >= QLEN - Kc) {
                int pos = list[total - QLEN + t];
                ii = (float)(pos >> 10);
                jj = (float)(pos & (TT - 1));
            }
            outq[2 * t] = ii;
            outq[2 * t + 1] = jj;
        }
        return;
    }

    const int p = wv & 3;            // pair id = batch slot
    const int b = blk * 4 + p;
    __shared__ float ring[4][2][UU][GG];                 // 32 KB xg rings
    __shared__ __align__(16) float hring[4][2][UU][DD];  // 8 KB h rings
    const int* idsb = ids + b * TT;

    if (wv >= 4) {
        // ---------- producer: xg 8 tokens ahead + cvt of chunk-1 -----------
        const int ja = l, jb = l + 64;
        floatx2 kp[DD];
#pragma unroll
        for (int d2 = 0; d2 < DD; ++d2)
            kp[d2] = (floatx2){klstm[d2 * GG + ja], klstm[d2 * GG + jb]};
        const floatx2 bj = (floatx2){bias[ja], bias[jb]};
        const int dd = l & 31;
        // cvt lane mappings
        const int u_r = l >> 3, dc = (l & 7) * 4;        // row side: 8B u16 runs
        const int d_c = l & 31, ug = (l >> 5) * 4;       // col side: 4 consecutive t
        u16* hhb = hh + (size_t)b * TT * DD;
        u16* hlb = hl + (size_t)b * TT * DD;
        u16* thb = th + (size_t)b * DD * TT;
        u16* tlb = tl + (size_t)b * DD * TT;

#define PROD_TOKEN(SEL, U, EV)                                               \
        {                                                                    \
            floatx2 z0 = bj;                                                 \
            floatx2 z1 = {0.f, 0.f}, z2 = {0.f, 0.f}, z3 = {0.f, 0.f};       \
            _Pragma("unroll")                                                \
            for (int k = 0; k < DD; k += 4) {                                \
                float e0 = readlane_f(EV, k);                                \
                float e1 = readlane_f(EV, k + 1);                            \
                float e2 = readlane_f(EV, k + 2);                            \
                float e3 = readlane_f(EV, k + 3);                            \
                z0 = fma2(e0, kp[k], z0);                                    \
                z1 = fma2(e1, kp[k + 1], z1);                                \
                z2 = fma2(e2, kp[k + 2], z2);                                \
                z3 = fma2(e3, kp[k + 3], z3);                                \
            }                                                                \
            floatx2 zf = (z0 + z1) + (z2 + z3);                              \
            ring[p][SEL][U][ja] = zf.x;                                      \
            ring[p][SEL][U][jb] = zf.y;                                      \
        }

        // convert chunk starting at token TC0 from hring[p][HSEL]
#define CVT_CHUNK(HSEL, TC0)                                                 \
        {                                                                    \
            const float4 hv4 = *(const float4*)&hring[p][HSEL][u_r][dc];     \
            float xr[4] = {hv4.x, hv4.y, hv4.z, hv4.w};                      \
            u16 rh[4], rl[4];                                                \
            _Pragma("unroll")                                                \
            for (int i = 0; i < 4; ++i) {                                    \
                rh[i] = f2bf_rne(xr[i]);                                     \
                rl[i] = f2bf_rne(xr[i] - bf2f(rh[i]));                       \
            }                                                                \
            ushort4 rhv = {rh[0], rh[1], rh[2], rh[3]};                      \
            ushort4 rlv = {rl[0], rl[1], rl[2], rl[3]};                      \
            *(ushort4*)&hhb[(size_t)((TC0) + u_r) * DD + dc] = rhv;          \
            *(ushort4*)&hlb[(size_t)((TC0) + u_r) * DD + dc] = rlv;          \
            u16 ch[4], cl[4];                                                \
            _Pragma("unroll")                                                \
            for (int j = 0; j < 4; ++j) {                                    \
                float x = hring[p][HSEL][ug + j][d_c];                       \
                ch[j] = f2bf_rne(x);                                         \
                cl[j] = f2bf_rne(x - bf2f(ch[j]));                           \
            }                                                                \
            ushort4 chv = {ch[0], ch[1], ch[2], ch[3]};                      \
            ushort4 clv = {cl[0], cl[1], cl[2], cl[3]};                      \
            *(ushort4*)&thb[(size_t)d_c * TT + (TC0) + ug] = chv;            \
            *(ushort4*)&tlb[(size_t)d_c * TT + (TC0) + ug] = clv;            \
        }

        {
            int id0 = idsb[0]; if ((unsigned)id0 >= VOCABN) id0 = 0;
            float ec = emb[id0 * DD + dd];
#pragma unroll
            for (int u = 0; u < UU; ++u) {
                float en = 0.f;
                if (u + 1 < UU) {
                    int idn = idsb[u + 1]; if ((unsigned)idn >= VOCABN) idn = 0;
                    en = emb[idn * DD + dd];
                }
                PROD_TOKEN(0, u, ec)
                ec = en;
            }
        }
        __syncthreads();
        int sel = 0;
        for (int t0 = 0; t0 < TT; t0 += UU) {
            if (t0 + UU < TT) {
                const int s = sel ^ 1;
                int id0 = idsb[t0 + UU]; if ((unsigned)id0 >= VOCABN) id0 = 0;
                float ec = emb[id0 * DD + dd];
#pragma unroll
                for (int u = 0; u < UU; ++u) {
                    float en = 0.f;
                    if (u + 1 < UU) {
                        int tn = t0 + UU + u + 1;
                        if (tn > TT - 1) tn = TT - 1;
                        int idn = idsb[tn]; if ((unsigned)idn >= VOCABN) idn = 0;
                        en = emb[idn * DD + dd];
                    }
                    PROD_TOKEN(s, u, ec)
                    ec = en;
                }
            }
            // cvt previous chunk (consumer wrote hring[p][(t0/UU-1)&1] before
            // the last barrier)
            if (t0) CVT_CHUNK((t0 / UU - 1) & 1, t0 - UU)
            __syncthreads();
            sel ^= 1;
        }
        // epilogue: convert the final chunk (written before the last barrier)
        CVT_CHUNK(1, TT - UU)
#undef PROD_TOKEN
#undef CVT_CHUNK
        return;
    }

    // ---------------- consumer: R21-exact scan + pk_fma dots ----------------
    const int d = l & 31;
    const bool hi = l >= 32;
    const int ga = (hi ? 32 : 0) + d;
    const int gb = (hi ? 96 : 64) + d;
    floatx2 rkp[DD];
#pragma unroll
    for (int k = 0; k < DD; ++k)
        rkp[k] = (floatx2){rk[k * GG + ga], rk[k * GG + gb]};
    float* hb = hout + (size_t)b * TT * DD;

    float h = 0.0f, c = 0.0f;
    float hreg[UU];
    __syncthreads();   // matches producer prologue barrier
    int sel = 0;
    for (int t0 = 0; t0 < TT; t0 += UU) {
        // flush previous chunk's h first: stores retire under this chunk's
        // compute, so the chunk-end barrier's vmcnt(0) drain is free.
        if (t0 && !hi) {
#pragma unroll
            for (int u = 0; u < UU; ++u) hb[(size_t)(t0 - UU + u) * DD + d] = hreg[u];
        }
        float pa[UU], pb[UU];
#pragma unroll
        for (int u = 0; u < UU; ++u) {
            pa[u] = ring[p][sel][u][ga];
            pb[u] = ring[p][sel][u][gb];
        }
#pragma unroll
        for (int u = 0; u < UU; ++u) {
            floatx2 x0 = {pa[u], pb[u]};
            floatx2 x1 = {0.f, 0.f}, x2 = {0.f, 0.f}, x3 = {0.f, 0.f};
#pragma unroll
            for (int k = 0; k < DD; k += 4) {
                float h0 = readlane_f(h, k);
                float h1 = readlane_f(h, k + 1);
                float h2 = readlane_f(h, k + 2);
                float h3 = readlane_f(h, k + 3);
                x0 = fma2(h0, rkp[k],     x0);
                x1 = fma2(h1, rkp[k + 1], x1);
                x2 = fma2(h2, rkp[k + 2], x2);
                x3 = fma2(h3, rkp[k + 3], x3);
            }
            floatx2 zf = (x0 + x1) + (x2 + x3);
            float za = zf.x, zb = zf.y;
            float a = fsig(za);                       // sig(i) lo / sig(f) hi
            float zbm = hi ? zb : 2.0f * zb;
            float s2 = fsig(zbm);
            float bv = hi ? s2 : 2.0f * s2 - 1.0f;    // sig(o) hi / tanh(g) lo
            // lane<32 <-> lane+32 exchange via v_permlane32_swap_b32 (VALU).
            auto r1 = __builtin_amdgcn_permlane32_swap(
                __float_as_int(bv), __float_as_int(a), false, false);
            auto r2 = __builtin_amdgcn_permlane32_swap(
                __float_as_int(a), __float_as_int(bv), false, false);
            float fg = __int_as_float(r1[0]);
            float og = __int_as_float(r2[0]);
            c = fmaf(fg, c, a * bv);
            float tc = 2.0f * fsig(2.0f * c) - 1.0f;
            h = og * tc;
            hreg[u] = h;
            if (!hi) hring[p][sel][u][d] = h;   // h ring for producer-side cvt
        }
        __syncthreads();
        sel ^= 1;
    }
    if (!hi) {
#pragma unroll
        for (int u = 0; u < UU; ++u) hb[(size_t)(TT - UU + u) * DD + d] = hreg[u];
    }
}

// ---------------------------------------------------------------------------
// Kernel 3: attention — R22 version (2 q-tiles/wave), unchanged.
// ---------------------------------------------------------------------------
__global__ __launch_bounds__(256, 2) void k_attn(const u16* __restrict__ hh,
                                                 const u16* __restrict__ hl,
                                                 const u16* __restrict__ th,
                                                 const u16* __restrict__ tl,
                                                 float* __restrict__ ctx) {
    __shared__ u16 plds[4][2][2][16 * 40];   // [wave][tile][dbuf][16x40]
    const int tid = threadIdx.x;
    const int w = tid >> 6;
    const int l = tid & 63;
    const int m = l & 15;
    const int g = l >> 4;
    const int b = blockIdx.x & 63;              // XCD swizzle: XCD = b % 8
    const int qt = (blockIdx.x >> 6) * 4 + w;   // 32-row wave tile, 0..31
    const int q0 = qt * 32;
    const size_t rb = (size_t)b * TT * DD;
    const size_t tb = (size_t)b * DD * TT;

    const short8 Qh0 = *(const short8*)&hh[rb + (size_t)(q0 + m) * DD + g * 8];
    const short8 Ql0 = *(const short8*)&hl[rb + (size_t)(q0 + m) * DD + g * 8];
    const short8 Qh1 = *(const short8*)&hh[rb + (size_t)(q0 + 16 + m) * DD + g * 8];
    const short8 Ql1 = *(const short8*)&hl[rb + (size_t)(q0 + 16 + m) * DD + g * 8];
    short8 ONES;
#pragma unroll
    for (int j = 0; j < 8; ++j) ONES[j] = (short)0x3F80;

    floatx4 c0 = {0.f, 0.f, 0.f, 0.f};   // tile0 cols 0-15
    floatx4 c1 = {0.f, 0.f, 0.f, 0.f};   // tile0 cols 16-31
    floatx4 c2 = {0.f, 0.f, 0.f, 0.f};   // tile1 cols 0-15
    floatx4 c3 = {0.f, 0.f, 0.f, 0.f};   // tile1 cols 16-31
    floatx4 la0 = {0.f, 0.f, 0.f, 0.f};
    floatx4 la1 = {0.f, 0.f, 0.f, 0.f};

#define S_BLOCK(QH, QL, KH_A, KL_A, KH_B, KL_B, SA, SB)                       \
    SA = __builtin_amdgcn_mfma_f32_16x16x32_bf16(QH, KH_A, SA, 0, 0, 0);      \
    SA = __builtin_amdgcn_mfma_f32_16x16x32_bf16(QH, KL_A, SA, 0, 0, 0);      \
    SA = __builtin_amdgcn_mfma_f32_16x16x32_bf16(QL, KH_A, SA, 0, 0, 0);      \
    SB = __builtin_amdgcn_mfma_f32_16x16x32_bf16(QH, KH_B, SB, 0, 0, 0);      \
    SB = __builtin_amdgcn_mfma_f32_16x16x32_bf16(QH, KL_B, SB, 0, 0, 0);      \
    SB = __builtin_amdgcn_mfma_f32_16x16x32_bf16(QL, KH_B, SB, 0, 0, 0);

    // ---- kp = 0: S + exp + write slot0 for BOTH tiles; no PV yet ----
    {
        short8 KhA = *(const short8*)&hh[rb + (size_t)(m) * DD + g * 8];
        short8 KlA = *(const short8*)&hl[rb + (size_t)(m) * DD + g * 8];
        short8 KhB = *(const short8*)&hh[rb + (size_t)(16 + m) * DD + g * 8];
        short8 KlB = *(const short8*)&hl[rb + (size_t)(16 + m) * DD + g * 8];
        floatx4 sA = {0.f, 0.f, 0.f, 0.f};
        floatx4 sB = {0.f, 0.f, 0.f, 0.f};
        floatx4 tA = {0.f, 0.f, 0.f, 0.f};
        floatx4 tB = {0.f, 0.f, 0.f, 0.f};
        S_BLOCK(Qh0, Ql0, KhA, KlA, KhB, KlB, sA, sB)
        S_BLOCK(Qh1, Ql1, KhA, KlA, KhB, KlB, tA, tB)
        u16* p0 = plds[w][0][0];
        u16* p1 = plds[w][1][0];
#pragma unroll
        for (int r = 0; r < 4; ++r) {
            p0[(g * 4 + r) * 40 + m]      = f2bf_rne(__expf(sA[r]));
            p0[(g * 4 + r) * 40 + 16 + m] = f2bf_rne(__expf(sB[r]));
            p1[(g * 4 + r) * 40 + m]      = f2bf_rne(__expf(tA[r]));
            p1[(g * 4 + r) * 40 + 16 + m] = f2bf_rne(__expf(tB[r]));
        }
    }
    // preload V_0 (used at kp=1) and K_1 — shared by both tiles
    short8 Vh0 = *(const short8*)&th[tb + (size_t)m * TT + g * 8];
    short8 Vl0 = *(const short8*)&tl[tb + (size_t)m * TT + g * 8];
    short8 Vh1 = *(const short8*)&th[tb + (size_t)(16 + m) * TT + g * 8];
    short8 Vl1 = *(const short8*)&tl[tb + (size_t)(16 + m) * TT + g * 8];
    short8 KhA = *(const short8*)&hh[rb + (size_t)(32 + m) * DD + g * 8];
    short8 KlA = *(const short8*)&hl[rb + (size_t)(32 + m) * DD + g * 8];
    short8 KhB = *(const short8*)&hh[rb + (size_t)(48 + m) * DD + g * 8];
    short8 KlB = *(const short8*)&hl[rb + (size_t)(48 + m) * DD + g * 8];

#pragma unroll 1
    for (int kp = 1; kp < 32; ++kp) {
        const int knK = (kp < 31) ? (kp + 1) * 32 : 0;
        const int knV = kp * 32;
        short8 nKhA = *(const short8*)&hh[rb + (size_t)(knK + m) * DD + g * 8];
        short8 nKlA = *(const short8*)&hl[rb + (size_t)(knK + m) * DD + g * 8];
        short8 nKhB = *(const short8*)&hh[rb + (size_t)(knK + 16 + m) * DD + g * 8];
        short8 nKlB = *(const short8*)&hl[rb + (size_t)(knK + 16 + m) * DD + g * 8];
        short8 nVh0 = *(const short8*)&th[tb + (size_t)m * TT + knV + g * 8];
        short8 nVl0 = *(const short8*)&tl[tb + (size_t)m * TT + knV + g * 8];
        short8 nVh1 = *(const short8*)&th[tb + (size_t)(16 + m) * TT + knV + g * 8];
        short8 nVl1 = *(const short8*)&tl[tb + (size_t)(16 + m) * TT + knV + g * 8];

        floatx4 sA = {0.f, 0.f, 0.f, 0.f};
        floatx4 sB = {0.f, 0.f, 0.f, 0.f};
        floatx4 tA = {0.f, 0.f, 0.f, 0.f};
        floatx4 tB = {0.f, 0.f, 0.f, 0.f};
        S_BLOCK(Qh0, Ql0, KhA, KlA, KhB, KlB, sA, sB)
        S_BLOCK(Qh1, Ql1, KhA, KlA, KhB, KlB, tA, tB)

        const short8 P0 = *(const short8*)&plds[w][0][(kp - 1) & 1][m * 40 + g * 8];
        const short8 P1 = *(const short8*)&plds[w][1][(kp - 1) & 1][m * 40 + g * 8];

        u16 pe0[8], pe1[8];
#pragma unroll
        for (int r = 0; r < 4; ++r) {
            pe0[r]     = f2bf_rne(__expf(sA[r]));
            pe0[4 + r] = f2bf_rne(__expf(sB[r]));
            pe1[r]     = f2bf_rne(__expf(tA[r]));
            pe1[4 + r] = f2bf_rne(__expf(tB[r]));
        }

        c0  = __builtin_amdgcn_mfma_f32_16x16x32_bf16(P0, Vh0, c0, 0, 0, 0);
        c0  = __builtin_amdgcn_mfma_f32_16x16x32_bf16(P0, Vl0, c0, 0, 0, 0);
        c1  = __builtin_amdgcn_mfma_f32_16x16x32_bf16(P0, Vh1, c1, 0, 0, 0);
        c1  = __builtin_amdgcn_mfma_f32_16x16x32_bf16(P0, Vl1, c1, 0, 0, 0);
        la0 = __builtin_amdgcn_mfma_f32_16x16x32_bf16(P0, ONES, la0, 0, 0, 0);
        c2  = __builtin_amdgcn_mfma_f32_16x16x32_bf16(P1, Vh0, c2, 0, 0, 0);
        c2  = __builtin_amdgcn_mfma_f32_16x16x32_bf16(P1, Vl0, c2, 0, 0, 0);
        c3  = __builtin_amdgcn_mfma_f32_16x16x32_bf16(P1, Vh1, c3, 0, 0, 0);
        c3  = __builtin_amdgcn_mfma_f32_16x16x32_bf16(P1, Vl1, c3, 0, 0, 0);
        la1 = __builtin_amdgcn_mfma_f32_16x16x32_bf16(P1, ONES, la1, 0, 0, 0);

        u16* w0 = plds[w][0][kp & 1];
        u16* w1 = plds[w][1][kp & 1];
#pragma unroll
        for (int r = 0; r < 4; ++r) {
            w0[(g * 4 + r) * 40 + m]      = pe0[r];
            w0[(g * 4 + r) * 40 + 16 + m] = pe0[4 + r];
            w1[(g * 4 + r) * 40 + m]      = pe1[r];
            w1[(g * 4 + r) * 40 + 16 + m] = pe1[4 + r];
        }

        KhA = nKhA; KlA = nKlA; KhB = nKhB; KlB = nKlB;
        Vh0 = nVh0; Vl0 = nVl0; Vh1 = nVh1; Vl1 = nVl1;
    }
    // epilogue: PV of kp=31 for both tiles
    {
        const short8 P0 = *(const short8*)&plds[w][0][31 & 1][m * 40 + g * 8];
        const short8 P1 = *(const short8*)&plds[w][1][31 & 1][m * 40 + g * 8];
        c0  = __builtin_amdgcn_mfma_f32_16x16x32_bf16(P0, Vh0, c0, 0, 0, 0);
        c0  = __builtin_amdgcn_mfma_f32_16x16x32_bf16(P0, Vl0, c0, 0, 0, 0);
        c1  = __builtin_amdgcn_mfma_f32_16x16x32_bf16(P0, Vh1, c1, 0, 0, 0);
        c1  = __builtin_amdgcn_mfma_f32_16x16x32_bf16(P0, Vl1, c1, 0, 0, 0);
        la0 = __builtin_amdgcn_mfma_f32_16x16x32_bf16(P0, ONES, la0, 0, 0, 0);
        c2  = __builtin_amdgcn_mfma_f32_16x16x32_bf16(P1, Vh0, c2, 0, 0, 0);
        c2  = __builtin_amdgcn_mfma_f32_16x16x32_bf16(P1, Vl0, c2, 0, 0, 0);
        c3  = __builtin_amdgcn_mfma_f32_16x16x32_bf16(P1, Vh1, c3, 0, 0, 0);
        c3  = __builtin_amdgcn_mfma_f32_16x16x32_bf16(P1, Vl1, c3, 0, 0, 0);
        la1 = __builtin_amdgcn_mfma_f32_16x16x32_bf16(P1, ONES, la1, 0, 0, 0);
    }
#undef S_BLOCK
#pragma unroll
    for (int r = 0; r < 4; ++r) {
        float li0 = __builtin_amdgcn_rcpf(la0[r]);
        float li1 = __builtin_amdgcn_rcpf(la1[r]);
        float* cr0 = ctx + (size_t)b * TT * DD + (size_t)(q0 + g * 4 + r) * DD;
        float* cr1 = ctx + (size_t)b * TT * DD + (size_t)(q0 + 16 + g * 4 + r) * DD;
        cr0[m]      = c0[r] * li0;
        cr0[16 + m] = c1[r] * li0;
        cr1[m]      = c2[r] * li1;
        cr1[16 + m] = c3[r] * li1;
    }
}

// ---------------------------------------------------------------------------
// Kernel 4: ymlp — R13 version, unchanged.
// ---------------------------------------------------------------------------
__global__ __launch_bounds__(256) void k_ymlp(const float* __restrict__ ctx,
                                              const float* __restrict__ h,
                                              const float* __restrict__ W1,
                                              const float* __restrict__ b1,
                                              const float* __restrict__ W2,
                                              const float* __restrict__ b2,
                                              float* __restrict__ out) {
    const int b = blockIdx.x;
    const int tid = threadIdx.x;
    __shared__ __align__(16) float cs[128 * DD];
    __shared__ __align__(16) float hs[128 * DD];
    const float* cb = ctx + (size_t)b * TT * DD;
    const float* hb = h + (size_t)b * TT * DD;
    const int e = tid & 31;
    const int d4 = (tid >> 5) * 4;
    float acc[4] = {0.f, 0.f, 0.f, 0.f};
    for (int kt = 0; kt < 8; ++kt) {
        const float4* s1 = (const float4*)(cb + (size_t)kt * 128 * DD);
        const float4* s2 = (const float4*)(hb + (size_t)kt * 128 * DD);
        float4* t1 = (float4*)cs;
        float4* t2 = (float4*)hs;
#pragma unroll
        for (int n = 0; n < 4; ++n) {
            t1[tid + n * 256] = s1[tid + n * 256];
            t2[tid + n * 256] = s2[tid + n * 256];
        }
        __syncthreads();
#pragma unroll 2
        for (int s = 0; s < 128; ++s) {
            float hv = hs[s * DD + e];
            float4 cv = *(const float4*)&cs[s * DD + d4];
            acc[0] = fmaf(cv.x, hv, acc[0]);
            acc[1] = fmaf(cv.y, hv, acc[1]);
            acc[2] = fmaf(cv.z, hv, acc[2]);
            acc[3] = fmaf(cv.w, hv, acc[3]);
        }
        __syncthreads();
    }
    __shared__ float ys[DD][DD];
#pragma unroll
    for (int r = 0; r < 4; ++r) ys[d4 + r][e] = acc[r];
    __syncthreads();
    __shared__ float yr[DD][33];
#pragma unroll
    for (int r = 0; r < 4; ++r) {
        float v = b1[e];
#pragma unroll
        for (int ee = 0; ee < DD; ++ee) v += ys[d4 + r][ee] * W1[ee * DD + e];
        yr[d4 + r][e] = fmaxf(v, 0.0f);
    }
    __syncthreads();
    if (tid < DD) {
        float v = b2[0];
#pragma unroll
        for (int ee = 0; ee < DD; ++ee) v += yr[tid][ee] * W2[ee];
        out[b * DD + tid] = 1.0f / (1.0f + expf(-v));
    }
}

// ---------------------------------------------------------------------------
extern "C" void kernel_launch(void* const* d_in, const int* in_sizes, int n_in,
                              void* d_out, int out_size, void* d_ws, size_t ws_size,
                              hipStream_t stream) {
    const int* ids   = (const int*)d_in[0];
    const float* emb = (const float*)d_in[1];
    const float* kl  = (const float*)d_in[2];
    const float* rk  = (const float*)d_in[3];
    const float* bl  = (const float*)d_in[4];
    const float* W1  = (const float*)d_in[5];
    const float* b1  = (const float*)d_in[6];
    const float* W2  = (const float*)d_in[7];
    const float* b2  = (const float*)d_in[8];
    float* out = (float*)d_out;

    char* ws = (char*)d_ws;
    const size_t H_ELEMS = (size_t)BB * TT * DD;   // 2,097,152
    u16* hh   = (u16*)ws;
    u16* hl   = (u16*)(ws + H_ELEMS * 2);
    u16* th   = (u16*)(ws + H_ELEMS * 4);
    u16* tl   = (u16*)(ws + H_ELEMS * 6);
    float* h  = (float*)(ws + H_ELEMS * 8);
    float* ctx = (float*)(ws + H_ELEMS * 8 + H_ELEMS * 4);
    int* list = (int*)(ws + H_ELEMS * 8 + H_ELEMS * 8);

    k_lstm_scan<<<BB / 4 + 1, 512, 0, stream>>>(ids, emb, kl, bl, rk, h,
                                                hh, hl, th, tl, list, out + BB * DD);
    k_attn<<<BB * 8, 256, 0, stream>>>(hh, hl, th, tl, ctx);
    k_ymlp<<<BB, 256, 0, stream>>>(ctx, h, W1, b1, W2, b2, out);
}

// Round 8
// 383.085 us; speedup vs baseline: 1.4358x; 1.4193x over previous
//
#include <hip/hip_runtime.h>
#include <math.h>

#define BB 64
#define TT 1024
#define DD 32
#define GG 128   // 4*D
#define VOCABN 10000
#define QLEN 100

typedef short short8 __attribute__((ext_vector_type(8)));   // 8 bf16 in 4 VGPRs
typedef float floatx4 __attribute__((ext_vector_type(4)));
typedef float floatx2 __attribute__((ext_vector_type(2)));
typedef unsigned short u16;

__device__ __forceinline__ float fsig(float x) {
    return __builtin_amdgcn_rcpf(1.0f + __expf(-x));
}
__device__ __forceinline__ float readlane_f(float v, int l) {
    return __int_as_float(__builtin_amdgcn_readlane(__float_as_int(v), l));
}
__device__ __forceinline__ u16 f2bf_rne(float x) {
    unsigned u = __float_as_uint(x);
    u += 0x7FFF + ((u >> 16) & 1);
    return (u16)(u >> 16);
}
__device__ __forceinline__ float bf2f(u16 s) {
    return __uint_as_float(((unsigned)s) << 16);
}
// packed fma: one v_pk_fma_f32 for the {a,b}-gate pair. IEEE fma per half ->
// bit-exact vs two fmaf.
__device__ __forceinline__ floatx2 fma2(float s, floatx2 w, floatx2 acc) {
    return __builtin_elementwise_fma((floatx2){s, s}, w, acc);
}

// ---------------------------------------------------------------------------
// Kernel 1: LSTM scan — R21-EXACT REVERT (measured 241 µs, VGPR 132).
// R23/R24 post-mortem: any 512-thread-group build loses the 132-VGPR
// allocation (60/88 VGPR -> weight arrays spill onto the serial chain,
// 398/392 µs). Co-residency abandoned; this 128-thread shape is the only
// one hipcc allocates correctly. pk_fma dots + permlane32_swap exchange +
// cvt fused into producer slack. Queue fused as blk 64 wave 0.
// ---------------------------------------------------------------------------
#define UU 8
__global__
__attribute__((amdgpu_flat_work_group_size(128, 128)))
__attribute__((amdgpu_waves_per_eu(1, 1)))
void k_lstm_scan(const int* __restrict__ ids,
                 const float* __restrict__ emb,
                 const float* __restrict__ klstm,
                 const float* __restrict__ bias,
                 const float* __restrict__ rk,
                 float* __restrict__ hout,
                 u16* __restrict__ hh, u16* __restrict__ hl,
                 u16* __restrict__ th, u16* __restrict__ tl,
                 int* __restrict__ list,
                 float* __restrict__ outq) {
    const int b = blockIdx.x;
    const int tid = threadIdx.x;
    const int wv = tid >> 6;   // wave 0 consumer / wave 1 producer+cvt
    const int l = tid & 63;
    if (b >= BB) {
        if (wv != 0) return;
        // ---- fused zero-index queue (single wave, no barriers) ----
        const int4* v4 = (const int4*)ids;
        const int C4 = (BB * TT) / 4 / 64;
        const int b4 = l * C4;
        int cnt = 0;
#pragma unroll 4
        for (int i = 0; i < C4; ++i) {
            int4 v = v4[b4 + i];
            cnt += (v.x == 0 || (unsigned)v.x >= VOCABN);
            cnt += (v.y == 0 || (unsigned)v.y >= VOCABN);
            cnt += (v.z == 0 || (unsigned)v.z >= VOCABN);
            cnt += (v.w == 0 || (unsigned)v.w >= VOCABN);
        }
        int scan = cnt;
#pragma unroll
        for (int o = 1; o < 64; o <<= 1) {
            int nn = __shfl_up(scan, o);
            if (l >= o) scan += nn;
        }
        const int total = __shfl(scan, 63);
        int off = scan - cnt;
        const int base = l * (C4 * 4);
#pragma unroll 4
        for (int i = 0; i < C4; ++i) {
            int4 v = v4[b4 + i];
            if (v.x == 0 || (unsigned)v.x >= VOCABN) list[off++] = base + 4 * i;
            if (v.y == 0 || (unsigned)v.y >= VOCABN) list[off++] = base + 4 * i + 1;
            if (v.z == 0 || (unsigned)v.z >= VOCABN) list[off++] = base + 4 * i + 2;
            if (v.w == 0 || (unsigned)v.w >= VOCABN) list[off++] = base + 4 * i + 3;
        }
        __threadfence();
        const int Kc = total < QLEN ? total : QLEN;
        for (int t = l; t < QLEN; t += 64) {
            float ii = -1.0f, jj = -1.0f;
            if (t >= QLEN - Kc) {
                int pos = list[total - QLEN + t];
                ii = (float)(pos >> 10);
                jj = (float)(pos & (TT - 1));
            }
            outq[2 * t] = ii;
            outq[2 * t + 1] = jj;
        }
        return;
    }

    __shared__ float ring[2][UU][GG];                    // 8 KB xg ring
    __shared__ __align__(16) float hring[2][UU][DD];     // 2 KB h ring (cvt)
    const int* idsb = ids + b * TT;

    if (wv == 1) {
        // ---------- producer: xg 8 tokens ahead + cvt of chunk-1 -----------
        const int ja = l, jb = l + 64;
        floatx2 kp[DD];
#pragma unroll
        for (int d2 = 0; d2 < DD; ++d2)
            kp[d2] = (floatx2){klstm[d2 * GG + ja], klstm[d2 * GG + jb]};
        const floatx2 bj = (floatx2){bias[ja], bias[jb]};
        const int dd = l & 31;
        // cvt lane mappings
        const int u_r = l >> 3, dc = (l & 7) * 4;        // row side: 8B u16 runs
        const int d_c = l & 31, ug = (l >> 5) * 4;       // col side: 4 consecutive t
        u16* hhb = hh + (size_t)b * TT * DD;
        u16* hlb = hl + (size_t)b * TT * DD;
        u16* thb = th + (size_t)b * DD * TT;
        u16* tlb = tl + (size_t)b * DD * TT;

#define PROD_TOKEN(SEL, U, EV)                                               \
        {                                                                    \
            floatx2 z0 = bj;                                                 \
            floatx2 z1 = {0.f, 0.f}, z2 = {0.f, 0.f}, z3 = {0.f, 0.f};       \
            _Pragma("unroll")                                                \
            for (int k = 0; k < DD; k += 4) {                                \
                float e0 = readlane_f(EV, k);                                \
                float e1 = readlane_f(EV, k + 1);                            \
                float e2 = readlane_f(EV, k + 2);                            \
                float e3 = readlane_f(EV, k + 3);                            \
                z0 = fma2(e0, kp[k], z0);                                    \
                z1 = fma2(e1, kp[k + 1], z1);                                \
                z2 = fma2(e2, kp[k + 2], z2);                                \
                z3 = fma2(e3, kp[k + 3], z3);                                \
            }                                                                \
            floatx2 zf = (z0 + z1) + (z2 + z3);                              \
            ring[SEL][U][ja] = zf.x;                                         \
            ring[SEL][U][jb] = zf.y;                                         \
        }

        // convert chunk starting at token TC0 from hring[HSEL]
#define CVT_CHUNK(HSEL, TC0)                                                 \
        {                                                                    \
            const float4 hv4 = *(const float4*)&hring[HSEL][u_r][dc];        \
            float xr[4] = {hv4.x, hv4.y, hv4.z, hv4.w};                      \
            u16 rh[4], rl[4];                                                \
            _Pragma("unroll")                                                \
            for (int i = 0; i < 4; ++i) {                                    \
                rh[i] = f2bf_rne(xr[i]);                                     \
                rl[i] = f2bf_rne(xr[i] - bf2f(rh[i]));                       \
            }                                                                \
            ushort4 rhv = {rh[0], rh[1], rh[2], rh[3]};                      \
            ushort4 rlv = {rl[0], rl[1], rl[2], rl[3]};                      \
            *(ushort4*)&hhb[(size_t)((TC0) + u_r) * DD + dc] = rhv;          \
            *(ushort4*)&hlb[(size_t)((TC0) + u_r) * DD + dc] = rlv;          \
            u16 ch[4], cl[4];                                                \
            _Pragma("unroll")                                                \
            for (int j = 0; j < 4; ++j) {                                    \
                float x = hring[HSEL][ug + j][d_c];                          \
                ch[j] = f2bf_rne(x);                                         \
                cl[j] = f2bf_rne(x - bf2f(ch[j]));                           \
            }                                                                \
            ushort4 chv = {ch[0], ch[1], ch[2], ch[3]};                      \
            ushort4 clv = {cl[0], cl[1], cl[2], cl[3]};                      \
            *(ushort4*)&thb[(size_t)d_c * TT + (TC0) + ug] = chv;            \
            *(ushort4*)&tlb[(size_t)d_c * TT + (TC0) + ug] = clv;            \
        }

        {
            int id0 = idsb[0]; if ((unsigned)id0 >= VOCABN) id0 = 0;
            float ec = emb[id0 * DD + dd];
#pragma unroll
            for (int u = 0; u < UU; ++u) {
                float en = 0.f;
                if (u + 1 < UU) {
                    int idn = idsb[u + 1]; if ((unsigned)idn >= VOCABN) idn = 0;
                    en = emb[idn * DD + dd];
                }
                PROD_TOKEN(0, u, ec)
                ec = en;
            }
        }
        __syncthreads();
        int sel = 0;
        for (int t0 = 0; t0 < TT; t0 += UU) {
            if (t0 + UU < TT) {
                const int s = sel ^ 1;
                int id0 = idsb[t0 + UU]; if ((unsigned)id0 >= VOCABN) id0 = 0;
                float ec = emb[id0 * DD + dd];
#pragma unroll
                for (int u = 0; u < UU; ++u) {
                    float en = 0.f;
                    if (u + 1 < UU) {
                        int tn = t0 + UU + u + 1;
                        if (tn > TT - 1) tn = TT - 1;
                        int idn = idsb[tn]; if ((unsigned)idn >= VOCABN) idn = 0;
                        en = emb[idn * DD + dd];
                    }
                    PROD_TOKEN(s, u, ec)
                    ec = en;
                }
            }
            // cvt previous chunk (consumer wrote hring[(t0/UU-1)&1] before
            // the last barrier)
            if (t0) CVT_CHUNK((t0 / UU - 1) & 1, t0 - UU)
            __syncthreads();
            sel ^= 1;
        }
        // epilogue: convert the final chunk (written before the last barrier)
        CVT_CHUNK(1, TT - UU)
#undef PROD_TOKEN
#undef CVT_CHUNK
        return;
    }

    // ---------------- consumer: R19-exact scan + pk_fma dots ----------------
    const int d = l & 31;
    const bool hi = l >= 32;
    const int ga = (hi ? 32 : 0) + d;
    const int gb = (hi ? 96 : 64) + d;
    floatx2 rkp[DD];
#pragma unroll
    for (int k = 0; k < DD; ++k)
        rkp[k] = (floatx2){rk[k * GG + ga], rk[k * GG + gb]};
    float* hb = hout + (size_t)b * TT * DD;

    float h = 0.0f, c = 0.0f;
    float hreg[UU];
    __syncthreads();   // matches producer prologue barrier
    int sel = 0;
    for (int t0 = 0; t0 < TT; t0 += UU) {
        // flush previous chunk's h first: stores retire under this chunk's
        // compute, so the chunk-end barrier's vmcnt(0) drain is free.
        if (t0 && !hi) {
#pragma unroll
            for (int u = 0; u < UU; ++u) hb[(size_t)(t0 - UU + u) * DD + d] = hreg[u];
        }
        float pa[UU], pb[UU];
#pragma unroll
        for (int u = 0; u < UU; ++u) {
            pa[u] = ring[sel][u][ga];
            pb[u] = ring[sel][u][gb];
        }
#pragma unroll
        for (int u = 0; u < UU; ++u) {
            floatx2 x0 = {pa[u], pb[u]};
            floatx2 x1 = {0.f, 0.f}, x2 = {0.f, 0.f}, x3 = {0.f, 0.f};
#pragma unroll
            for (int k = 0; k < DD; k += 4) {
                float h0 = readlane_f(h, k);
                float h1 = readlane_f(h, k + 1);
                float h2 = readlane_f(h, k + 2);
                float h3 = readlane_f(h, k + 3);
                x0 = fma2(h0, rkp[k],     x0);
                x1 = fma2(h1, rkp[k + 1], x1);
                x2 = fma2(h2, rkp[k + 2], x2);
                x3 = fma2(h3, rkp[k + 3], x3);
            }
            floatx2 zf = (x0 + x1) + (x2 + x3);
            float za = zf.x, zb = zf.y;
            float a = fsig(za);                       // sig(i) lo / sig(f) hi
            float zbm = hi ? zb : 2.0f * zb;
            float s2 = fsig(zbm);
            float bv = hi ? s2 : 2.0f * s2 - 1.0f;    // sig(o) hi / tanh(g) lo
            // lane<32 <-> lane+32 exchange via v_permlane32_swap_b32 (VALU).
            auto r1 = __builtin_amdgcn_permlane32_swap(
                __float_as_int(bv), __float_as_int(a), false, false);
            auto r2 = __builtin_amdgcn_permlane32_swap(
                __float_as_int(a), __float_as_int(bv), false, false);
            float fg = __int_as_float(r1[0]);
            float og = __int_as_float(r2[0]);
            c = fmaf(fg, c, a * bv);
            float tc = 2.0f * fsig(2.0f * c) - 1.0f;
            h = og * tc;
            hreg[u] = h;
            if (!hi) hring[sel][u][d] = h;   // h ring for producer-side cvt
        }
        __syncthreads();
        sel ^= 1;
    }
    if (!hi) {
#pragma unroll
        for (int u = 0; u < UU; ++u) hb[(size_t)(TT - UU + u) * DD + d] = hreg[u];
    }
}

// ---------------------------------------------------------------------------
// Kernel 3: attention — R25: FOUR q-tiles (64 q-rows) per wave. R16->R22
// showed this kernel responds to per-wave K/V reuse (16->32 rows: attn slice
// ~150 -> ~90 µs) and NOT to TLP (R16 had 2x TLP and lost). Double reuse
// again: same 8 loads/iter now feed 44 MFMAs; K/V traffic halves again.
// Grid BB*4 = 256 blocks (1/CU), launch_bounds(256,1) for the ~200-VGPR
// working set. Per-tile math op-for-op the verified R16/R22 scheme.
// ---------------------------------------------------------------------------
__global__ __launch_bounds__(256, 1) void k_attn(const u16* __restrict__ hh,
                                                 const u16* __restrict__ hl,
                                                 const u16* __restrict__ th,
                                                 const u16* __restrict__ tl,
                                                 float* __restrict__ ctx) {
    __shared__ u16 plds[4][4][2][16 * 40];   // [wave][tile][dbuf][16x40]
    const int tid = threadIdx.x;
    const int w = tid >> 6;
    const int l = tid & 63;
    const int m = l & 15;
    const int g = l >> 4;
    const int b = blockIdx.x & 63;              // XCD swizzle: XCD = b % 8
    const int qt = (blockIdx.x >> 6) * 4 + w;   // 64-row wave tile, 0..15
    const int q0 = qt * 64;
    const size_t rb = (size_t)b * TT * DD;
    const size_t tb = (size_t)b * DD * TT;

    const short8 Qh0 = *(const short8*)&hh[rb + (size_t)(q0 + m) * DD + g * 8];
    const short8 Ql0 = *(const short8*)&hl[rb + (size_t)(q0 + m) * DD + g * 8];
    const short8 Qh1 = *(const short8*)&hh[rb + (size_t)(q0 + 16 + m) * DD + g * 8];
    const short8 Ql1 = *(const short8*)&hl[rb + (size_t)(q0 + 16 + m) * DD + g * 8];
    const short8 Qh2 = *(const short8*)&hh[rb + (size_t)(q0 + 32 + m) * DD + g * 8];
    const short8 Ql2 = *(const short8*)&hl[rb + (size_t)(q0 + 32 + m) * DD + g * 8];
    const short8 Qh3 = *(const short8*)&hh[rb + (size_t)(q0 + 48 + m) * DD + g * 8];
    const short8 Ql3 = *(const short8*)&hl[rb + (size_t)(q0 + 48 + m) * DD + g * 8];
    short8 ONES;
#pragma unroll
    for (int j = 0; j < 8; ++j) ONES[j] = (short)0x3F80;

    floatx4 c0 = {0.f, 0.f, 0.f, 0.f}, c1 = {0.f, 0.f, 0.f, 0.f};
    floatx4 c2 = {0.f, 0.f, 0.f, 0.f}, c3 = {0.f, 0.f, 0.f, 0.f};
    floatx4 c4 = {0.f, 0.f, 0.f, 0.f}, c5 = {0.f, 0.f, 0.f, 0.f};
    floatx4 c6 = {0.f, 0.f, 0.f, 0.f}, c7 = {0.f, 0.f, 0.f, 0.f};
    floatx4 la0 = {0.f, 0.f, 0.f, 0.f}, la1 = {0.f, 0.f, 0.f, 0.f};
    floatx4 la2 = {0.f, 0.f, 0.f, 0.f}, la3 = {0.f, 0.f, 0.f, 0.f};

#define S_BLOCK(QH, QL, KH_A, KL_A, KH_B, KL_B, SA, SB)                       \
    SA = __builtin_amdgcn_mfma_f32_16x16x32_bf16(QH, KH_A, SA, 0, 0, 0);      \
    SA = __builtin_amdgcn_mfma_f32_16x16x32_bf16(QH, KL_A, SA, 0, 0, 0);      \
    SA = __builtin_amdgcn_mfma_f32_16x16x32_bf16(QL, KH_A, SA, 0, 0, 0);      \
    SB = __builtin_amdgcn_mfma_f32_16x16x32_bf16(QH, KH_B, SB, 0, 0, 0);      \
    SB = __builtin_amdgcn_mfma_f32_16x16x32_bf16(QH, KL_B, SB, 0, 0, 0);      \
    SB = __builtin_amdgcn_mfma_f32_16x16x32_bf16(QL, KH_B, SB, 0, 0, 0);

#define EXP_STORE(SA, SB, TILE, SLOT)                                         \
    {                                                                         \
        u16* lp = plds[w][TILE][SLOT];                                        \
        _Pragma("unroll")                                                     \
        for (int r = 0; r < 4; ++r) {                                         \
            lp[(g * 4 + r) * 40 + m]      = f2bf_rne(__expf(SA[r]));          \
            lp[(g * 4 + r) * 40 + 16 + m] = f2bf_rne(__expf(SB[r]));          \
        }                                                                     \
    }

    // ---- kp = 0: S + exp + write slot0 for all four tiles; no PV yet ----
    {
        short8 KhA = *(const short8*)&hh[rb + (size_t)(m) * DD + g * 8];
        short8 KlA = *(const short8*)&hl[rb + (size_t)(m) * DD + g * 8];
        short8 KhB = *(const short8*)&hh[rb + (size_t)(16 + m) * DD + g * 8];
        short8 KlB = *(const short8*)&hl[rb + (size_t)(16 + m) * DD + g * 8];
        floatx4 sA = {0.f, 0.f, 0.f, 0.f}, sB = {0.f, 0.f, 0.f, 0.f};
        floatx4 tA = {0.f, 0.f, 0.f, 0.f}, tB = {0.f, 0.f, 0.f, 0.f};
        floatx4 uA = {0.f, 0.f, 0.f, 0.f}, uB = {0.f, 0.f, 0.f, 0.f};
        floatx4 vA = {0.f, 0.f, 0.f, 0.f}, vB = {0.f, 0.f, 0.f, 0.f};
        S_BLOCK(Qh0, Ql0, KhA, KlA, KhB, KlB, sA, sB)
        S_BLOCK(Qh1, Ql1, KhA, KlA, KhB, KlB, tA, tB)
        S_BLOCK(Qh2, Ql2, KhA, KlA, KhB, KlB, uA, uB)
        S_BLOCK(Qh3, Ql3, KhA, KlA, KhB, KlB, vA, vB)
        EXP_STORE(sA, sB, 0, 0)
        EXP_STORE(tA, tB, 1, 0)
        EXP_STORE(uA, uB, 2, 0)
        EXP_STORE(vA, vB, 3, 0)
    }
    // preload V_0 (used at kp=1) and K_1 — shared by all four tiles
    short8 Vh0 = *(const short8*)&th[tb + (size_t)m * TT + g * 8];
    short8 Vl0 = *(const short8*)&tl[tb + (size_t)m * TT + g * 8];
    short8 Vh1 = *(const short8*)&th[tb + (size_t)(16 + m) * TT + g * 8];
    short8 Vl1 = *(const short8*)&tl[tb + (size_t)(16 + m) * TT + g * 8];
    short8 KhA = *(const short8*)&hh[rb + (size_t)(32 + m) * DD + g * 8];
    short8 KlA = *(const short8*)&hl[rb + (size_t)(32 + m) * DD + g * 8];
    short8 KhB = *(const short8*)&hh[rb + (size_t)(48 + m) * DD + g * 8];
    short8 KlB = *(const short8*)&hl[rb + (size_t)(48 + m) * DD + g * 8];

#pragma unroll 1
    for (int kp = 1; kp < 32; ++kp) {
        const int knK = (kp < 31) ? (kp + 1) * 32 : 0;
        const int knV = kp * 32;
        short8 nKhA = *(const short8*)&hh[rb + (size_t)(knK + m) * DD + g * 8];
        short8 nKlA = *(const short8*)&hl[rb + (size_t)(knK + m) * DD + g * 8];
        short8 nKhB = *(const short8*)&hh[rb + (size_t)(knK + 16 + m) * DD + g * 8];
        short8 nKlB = *(const short8*)&hl[rb + (size_t)(knK + 16 + m) * DD + g * 8];
        short8 nVh0 = *(const short8*)&th[tb + (size_t)m * TT + knV + g * 8];
        short8 nVl0 = *(const short8*)&tl[tb + (size_t)m * TT + knV + g * 8];
        short8 nVh1 = *(const short8*)&th[tb + (size_t)(16 + m) * TT + knV + g * 8];
        short8 nVl1 = *(const short8*)&tl[tb + (size_t)(16 + m) * TT + knV + g * 8];

        floatx4 sA = {0.f, 0.f, 0.f, 0.f}, sB = {0.f, 0.f, 0.f, 0.f};
        floatx4 tA = {0.f, 0.f, 0.f, 0.f}, tB = {0.f, 0.f, 0.f, 0.f};
        floatx4 uA = {0.f, 0.f, 0.f, 0.f}, uB = {0.f, 0.f, 0.f, 0.f};
        floatx4 vA = {0.f, 0.f, 0.f, 0.f}, vB = {0.f, 0.f, 0.f, 0.f};
        S_BLOCK(Qh0, Ql0, KhA, KlA, KhB, KlB, sA, sB)
        S_BLOCK(Qh1, Ql1, KhA, KlA, KhB, KlB, tA, tB)
        S_BLOCK(Qh2, Ql2, KhA, KlA, KhB, KlB, uA, uB)
        S_BLOCK(Qh3, Ql3, KhA, KlA, KhB, KlB, vA, vB)

        const int ps = (kp - 1) & 1;
        const short8 P0 = *(const short8*)&plds[w][0][ps][m * 40 + g * 8];
        const short8 P1 = *(const short8*)&plds[w][1][ps][m * 40 + g * 8];
        const short8 P2 = *(const short8*)&plds[w][2][ps][m * 40 + g * 8];
        const short8 P3 = *(const short8*)&plds[w][3][ps][m * 40 + g * 8];

        c0  = __builtin_amdgcn_mfma_f32_16x16x32_bf16(P0, Vh0, c0, 0, 0, 0);
        c0  = __builtin_amdgcn_mfma_f32_16x16x32_bf16(P0, Vl0, c0, 0, 0, 0);
        c1  = __builtin_amdgcn_mfma_f32_16x16x32_bf16(P0, Vh1, c1, 0, 0, 0);
        c1  = __builtin_amdgcn_mfma_f32_16x16x32_bf16(P0, Vl1, c1, 0, 0, 0);
        la0 = __builtin_amdgcn_mfma_f32_16x16x32_bf16(P0, ONES, la0, 0, 0, 0);
        c2  = __builtin_amdgcn_mfma_f32_16x16x32_bf16(P1, Vh0, c2, 0, 0, 0);
        c2  = __builtin_amdgcn_mfma_f32_16x16x32_bf16(P1, Vl0, c2, 0, 0, 0);
        c3  = __builtin_amdgcn_mfma_f32_16x16x32_bf16(P1, Vh1, c3, 0, 0, 0);
        c3  = __builtin_amdgcn_mfma_f32_16x16x32_bf16(P1, Vl1, c3, 0, 0, 0);
        la1 = __builtin_amdgcn_mfma_f32_16x16x32_bf16(P1, ONES, la1, 0, 0, 0);
        c4  = __builtin_amdgcn_mfma_f32_16x16x32_bf16(P2, Vh0, c4, 0, 0, 0);
        c4  = __builtin_amdgcn_mfma_f32_16x16x32_bf16(P2, Vl0, c4, 0, 0, 0);
        c5  = __builtin_amdgcn_mfma_f32_16x16x32_bf16(P2, Vh1, c5, 0, 0, 0);
        c5  = __builtin_amdgcn_mfma_f32_16x16x32_bf16(P2, Vl1, c5, 0, 0, 0);
        la2 = __builtin_amdgcn_mfma_f32_16x16x32_bf16(P2, ONES, la2, 0, 0, 0);
        c6  = __builtin_amdgcn_mfma_f32_16x16x32_bf16(P3, Vh0, c6, 0, 0, 0);
        c6  = __builtin_amdgcn_mfma_f32_16x16x32_bf16(P3, Vl0, c6, 0, 0, 0);
        c7  = __builtin_amdgcn_mfma_f32_16x16x32_bf16(P3, Vh1, c7, 0, 0, 0);
        c7  = __builtin_amdgcn_mfma_f32_16x16x32_bf16(P3, Vl1, c7, 0, 0, 0);
        la3 = __builtin_amdgcn_mfma_f32_16x16x32_bf16(P3, ONES, la3, 0, 0, 0);

        EXP_STORE(sA, sB, 0, kp & 1)
        EXP_STORE(tA, tB, 1, kp & 1)
        EXP_STORE(uA, uB, 2, kp & 1)
        EXP_STORE(vA, vB, 3, kp & 1)

        KhA = nKhA; KlA = nKlA; KhB = nKhB; KlB = nKlB;
        Vh0 = nVh0; Vl0 = nVl0; Vh1 = nVh1; Vl1 = nVl1;
    }
    // epilogue: PV of kp=31 for all four tiles
    {
        const short8 P0 = *(const short8*)&plds[w][0][1][m * 40 + g * 8];
        const short8 P1 = *(const short8*)&plds[w][1][1][m * 40 + g * 8];
        const short8 P2 = *(const short8*)&plds[w][2][1][m * 40 + g * 8];
        const short8 P3 = *(const short8*)&plds[w][3][1][m * 40 + g * 8];
        c0  = __builtin_amdgcn_mfma_f32_16x16x32_bf16(P0, Vh0, c0, 0, 0, 0);
        c0  = __builtin_amdgcn_mfma_f32_16x16x32_bf16(P0, Vl0, c0, 0, 0, 0);
        c1  = __builtin_amdgcn_mfma_f32_16x16x32_bf16(P0, Vh1, c1, 0, 0, 0);
        c1  = __builtin_amdgcn_mfma_f32_16x16x32_bf16(P0, Vl1, c1, 0, 0, 0);
        la0 = __builtin_amdgcn_mfma_f32_16x16x32_bf16(P0, ONES, la0, 0, 0, 0);
        c2  = __builtin_amdgcn_mfma_f32_16x16x32_bf16(P1, Vh0, c2, 0, 0, 0);
        c2  = __builtin_amdgcn_mfma_f32_16x16x32_bf16(P1, Vl0, c2, 0, 0, 0);
        c3  = __builtin_amdgcn_mfma_f32_16x16x32_bf16(P1, Vh1, c3, 0, 0, 0);
        c3  = __builtin_amdgcn_mfma_f32_16x16x32_bf16(P1, Vl1, c3, 0, 0, 0);
        la1 = __builtin_amdgcn_mfma_f32_16x16x32_bf16(P1, ONES, la1, 0, 0, 0);
        c4  = __builtin_amdgcn_mfma_f32_16x16x32_bf16(P2, Vh0, c4, 0, 0, 0);
        c4  = __builtin_amdgcn_mfma_f32_16x16x32_bf16(P2, Vl0, c4, 0, 0, 0);
        c5  = __builtin_amdgcn_mfma_f32_16x16x32_bf16(P2, Vh1, c5, 0, 0, 0);
        c5  = __builtin_amdgcn_mfma_f32_16x16x32_bf16(P2, Vl1, c5, 0, 0, 0);
        la2 = __builtin_amdgcn_mfma_f32_16x16x32_bf16(P2, ONES, la2, 0, 0, 0);
        c6  = __builtin_amdgcn_mfma_f32_16x16x32_bf16(P3, Vh0, c6, 0, 0, 0);
        c6  = __builtin_amdgcn_mfma_f32_16x16x32_bf16(P3, Vl0, c6, 0, 0, 0);
        c7  = __builtin_amdgcn_mfma_f32_16x16x32_bf16(P3, Vh1, c7, 0, 0, 0);
        c7  = __builtin_amdgcn_mfma_f32_16x16x32_bf16(P3, Vl1, c7, 0, 0, 0);
        la3 = __builtin_amdgcn_mfma_f32_16x16x32_bf16(P3, ONES, la3, 0, 0, 0);
    }
#undef S_BLOCK
#undef EXP_STORE
#pragma unroll
    for (int r = 0; r < 4; ++r) {
        float li0 = __builtin_amdgcn_rcpf(la0[r]);
        float li1 = __builtin_amdgcn_rcpf(la1[r]);
        float li2 = __builtin_amdgcn_rcpf(la2[r]);
        float li3 = __builtin_amdgcn_rcpf(la3[r]);
        float* cr0 = ctx + (size_t)b * TT * DD + (size_t)(q0 + g * 4 + r) * DD;
        float* cr1 = ctx + (size_t)b * TT * DD + (size_t)(q0 + 16 + g * 4 + r) * DD;
        float* cr2 = ctx + (size_t)b * TT * DD + (size_t)(q0 + 32 + g * 4 + r) * DD;
        float* cr3 = ctx + (size_t)b * TT * DD + (size_t)(q0 + 48 + g * 4 + r) * DD;
        cr0[m]      = c0[r] * li0;
        cr0[16 + m] = c1[r] * li0;
        cr1[m]      = c2[r] * li1;
        cr1[16 + m] = c3[r] * li1;
        cr2[m]      = c4[r] * li2;
        cr2[16 + m] = c5[r] * li2;
        cr3[m]      = c6[r] * li3;
        cr3[16 + m] = c7[r] * li3;
    }
}

// ---------------------------------------------------------------------------
// Kernel 4: ymlp — R13 version, unchanged.
// ---------------------------------------------------------------------------
__global__ __launch_bounds__(256) void k_ymlp(const float* __restrict__ ctx,
                                              const float* __restrict__ h,
                                              const float* __restrict__ W1,
                                              const float* __restrict__ b1,
                                              const float* __restrict__ W2,
                                              const float* __restrict__ b2,
                                              float* __restrict__ out) {
    const int b = blockIdx.x;
    const int tid = threadIdx.x;
    __shared__ __align__(16) float cs[128 * DD];
    __shared__ __align__(16) float hs[128 * DD];
    const float* cb = ctx + (size_t)b * TT * DD;
    const float* hb = h + (size_t)b * TT * DD;
    const int e = tid & 31;
    const int d4 = (tid >> 5) * 4;
    float acc[4] = {0.f, 0.f, 0.f, 0.f};
    for (int kt = 0; kt < 8; ++kt) {
        const float4* s1 = (const float4*)(cb + (size_t)kt * 128 * DD);
        const float4* s2 = (const float4*)(hb + (size_t)kt * 128 * DD);
        float4* t1 = (float4*)cs;
        float4* t2 = (float4*)hs;
#pragma unroll
        for (int n = 0; n < 4; ++n) {
            t1[tid + n * 256] = s1[tid + n * 256];
            t2[tid + n * 256] = s2[tid + n * 256];
        }
        __syncthreads();
#pragma unroll 2
        for (int s = 0; s < 128; ++s) {
            float hv = hs[s * DD + e];
            float4 cv = *(const float4*)&cs[s * DD + d4];
            acc[0] = fmaf(cv.x, hv, acc[0]);
            acc[1] = fmaf(cv.y, hv, acc[1]);
            acc[2] = fmaf(cv.z, hv, acc[2]);
            acc[3] = fmaf(cv.w, hv, acc[3]);
        }
        __syncthreads();
    }
    __shared__ float ys[DD][DD];
#pragma unroll
    for (int r = 0; r < 4; ++r) ys[d4 + r][e] = acc[r];
    __syncthreads();
    __shared__ float yr[DD][33];
#pragma unroll
    for (int r = 0; r < 4; ++r) {
        float v = b1[e];
#pragma unroll
        for (int ee = 0; ee < DD; ++ee) v += ys[d4 + r][ee] * W1[ee * DD + e];
        yr[d4 + r][e] = fmaxf(v, 0.0f);
    }
    __syncthreads();
    if (tid < DD) {
        float v = b2[0];
#pragma unroll
        for (int ee = 0; ee < DD; ++ee) v += yr[tid][ee] * W2[ee];
        out[b * DD + tid] = 1.0f / (1.0f + expf(-v));
    }
}

// ---------------------------------------------------------------------------
extern "C" void kernel_launch(void* const* d_in, const int* in_sizes, int n_in,
                              void* d_out, int out_size, void* d_ws, size_t ws_size,
                              hipStream_t stream) {
    const int* ids   = (const int*)d_in[0];
    const float* emb = (const float*)d_in[1];
    const float* kl  = (const float*)d_in[2];
    const float* rk  = (const float*)d_in[3];
    const float* bl  = (const float*)d_in[4];
    const float* W1  = (const float*)d_in[5];
    const float* b1  = (const float*)d_in[6];
    const float* W2  = (const float*)d_in[7];
    const float* b2  = (const float*)d_in[8];
    float* out = (float*)d_out;

    char* ws = (char*)d_ws;
    const size_t H_ELEMS = (size_t)BB * TT * DD;   // 2,097,152
    u16* hh   = (u16*)ws;
    u16* hl   = (u16*)(ws + H_ELEMS * 2);
    u16* th   = (u16*)(ws + H_ELEMS * 4);
    u16* tl   = (u16*)(ws + H_ELEMS * 6);
    float* h  = (float*)(ws + H_ELEMS * 8);
    float* ctx = (float*)(ws + H_ELEMS * 8 + H_ELEMS * 4);
    int* list = (int*)(ws + H_ELEMS * 8 + H_ELEMS * 8);

    k_lstm_scan<<<BB + 1, 128, 0, stream>>>(ids, emb, kl, bl, rk, h,
                                            hh, hl, th, tl, list, out + BB * DD);
    k_attn<<<BB * 4, 256, 0, stream>>>(hh, hl, th, tl, ctx);
    k_ymlp<<<BB, 256, 0, stream>>>(ctx, h, W1, b1, W2, b2, out);
}

// Round 9
// 366.466 us; speedup vs baseline: 1.5010x; 1.0453x over previous
//
#include <hip/hip_runtime.h>
#include <math.h>

#define BB 64
#define TT 1024
#define DD 32
#define GG 128   // 4*D
#define VOCABN 10000
#define QLEN 100

typedef short short8 __attribute__((ext_vector_type(8)));   // 8 bf16 in 4 VGPRs
typedef float floatx4 __attribute__((ext_vector_type(4)));
typedef float floatx2 __attribute__((ext_vector_type(2)));
typedef unsigned short u16;

__device__ __forceinline__ float fsig(float x) {
    return __builtin_amdgcn_rcpf(1.0f + __expf(-x));
}
__device__ __forceinline__ float readlane_f(float v, int l) {
    return __int_as_float(__builtin_amdgcn_readlane(__float_as_int(v), l));
}
__device__ __forceinline__ u16 f2bf_rne(float x) {
    unsigned u = __float_as_uint(x);
    u += 0x7FFF + ((u >> 16) & 1);
    return (u16)(u >> 16);
}
__device__ __forceinline__ float bf2f(u16 s) {
    return __uint_as_float(((unsigned)s) << 16);
}
// packed fma: one v_pk_fma_f32 for the {a,b}-gate pair. IEEE fma per half ->
// bit-exact vs two fmaf.
__device__ __forceinline__ floatx2 fma2(float s, floatx2 w, floatx2 acc) {
    return __builtin_elementwise_fma((floatx2){s, s}, w, acc);
}

// ---------------------------------------------------------------------------
// Kernel 1: LSTM scan — R21-EXACT (measured 241-257 µs, VGPR 132). DO NOT
// TOUCH: R23/R24 showed any reshape loses the 132-VGPR allocation and spills
// the weight arrays onto the serial chain. pk_fma dots + permlane32_swap +
// cvt fused into producer slack. Queue fused as blk 64 wave 0.
// ---------------------------------------------------------------------------
#define UU 8
__global__
__attribute__((amdgpu_flat_work_group_size(128, 128)))
__attribute__((amdgpu_waves_per_eu(1, 1)))
void k_lstm_scan(const int* __restrict__ ids,
                 const float* __restrict__ emb,
                 const float* __restrict__ klstm,
                 const float* __restrict__ bias,
                 const float* __restrict__ rk,
                 float* __restrict__ hout,
                 u16* __restrict__ hh, u16* __restrict__ hl,
                 u16* __restrict__ th, u16* __restrict__ tl,
                 int* __restrict__ list,
                 float* __restrict__ outq) {
    const int b = blockIdx.x;
    const int tid = threadIdx.x;
    const int wv = tid >> 6;   // wave 0 consumer / wave 1 producer+cvt
    const int l = tid & 63;
    if (b >= BB) {
        if (wv != 0) return;
        // ---- fused zero-index queue (single wave, no barriers) ----
        const int4* v4 = (const int4*)ids;
        const int C4 = (BB * TT) / 4 / 64;
        const int b4 = l * C4;
        int cnt = 0;
#pragma unroll 4
        for (int i = 0; i < C4; ++i) {
            int4 v = v4[b4 + i];
            cnt += (v.x == 0 || (unsigned)v.x >= VOCABN);
            cnt += (v.y == 0 || (unsigned)v.y >= VOCABN);
            cnt += (v.z == 0 || (unsigned)v.z >= VOCABN);
            cnt += (v.w == 0 || (unsigned)v.w >= VOCABN);
        }
        int scan = cnt;
#pragma unroll
        for (int o = 1; o < 64; o <<= 1) {
            int nn = __shfl_up(scan, o);
            if (l >= o) scan += nn;
        }
        const int total = __shfl(scan, 63);
        int off = scan - cnt;
        const int base = l * (C4 * 4);
#pragma unroll 4
        for (int i = 0; i < C4; ++i) {
            int4 v = v4[b4 + i];
            if (v.x == 0 || (unsigned)v.x >= VOCABN) list[off++] = base + 4 * i;
            if (v.y == 0 || (unsigned)v.y >= VOCABN) list[off++] = base + 4 * i + 1;
            if (v.z == 0 || (unsigned)v.z >= VOCABN) list[off++] = base + 4 * i + 2;
            if (v.w == 0 || (unsigned)v.w >= VOCABN) list[off++] = base + 4 * i + 3;
        }
        __threadfence();
        const int Kc = total < QLEN ? total : QLEN;
        for (int t = l; t < QLEN; t += 64) {
            float ii = -1.0f, jj = -1.0f;
            if (t >= QLEN - Kc) {
                int pos = list[total - QLEN + t];
                ii = (float)(pos >> 10);
                jj = (float)(pos & (TT - 1));
            }
            outq[2 * t] = ii;
            outq[2 * t + 1] = jj;
        }
        return;
    }

    __shared__ float ring[2][UU][GG];                    // 8 KB xg ring
    __shared__ __align__(16) float hring[2][UU][DD];     // 2 KB h ring (cvt)
    const int* idsb = ids + b * TT;

    if (wv == 1) {
        // ---------- producer: xg 8 tokens ahead + cvt of chunk-1 -----------
        const int ja = l, jb = l + 64;
        floatx2 kp[DD];
#pragma unroll
        for (int d2 = 0; d2 < DD; ++d2)
            kp[d2] = (floatx2){klstm[d2 * GG + ja], klstm[d2 * GG + jb]};
        const floatx2 bj = (floatx2){bias[ja], bias[jb]};
        const int dd = l & 31;
        // cvt lane mappings
        const int u_r = l >> 3, dc = (l & 7) * 4;        // row side: 8B u16 runs
        const int d_c = l & 31, ug = (l >> 5) * 4;       // col side: 4 consecutive t
        u16* hhb = hh + (size_t)b * TT * DD;
        u16* hlb = hl + (size_t)b * TT * DD;
        u16* thb = th + (size_t)b * DD * TT;
        u16* tlb = tl + (size_t)b * DD * TT;

#define PROD_TOKEN(SEL, U, EV)                                               \
        {                                                                    \
            floatx2 z0 = bj;                                                 \
            floatx2 z1 = {0.f, 0.f}, z2 = {0.f, 0.f}, z3 = {0.f, 0.f};       \
            _Pragma("unroll")                                                \
            for (int k = 0; k < DD; k += 4) {                                \
                float e0 = readlane_f(EV, k);                                \
                float e1 = readlane_f(EV, k + 1);                            \
                float e2 = readlane_f(EV, k + 2);                            \
                float e3 = readlane_f(EV, k + 3);                            \
                z0 = fma2(e0, kp[k], z0);                                    \
                z1 = fma2(e1, kp[k + 1], z1);                                \
                z2 = fma2(e2, kp[k + 2], z2);                                \
                z3 = fma2(e3, kp[k + 3], z3);                                \
            }                                                                \
            floatx2 zf = (z0 + z1) + (z2 + z3);                              \
            ring[SEL][U][ja] = zf.x;                                         \
            ring[SEL][U][jb] = zf.y;                                         \
        }

        // convert chunk starting at token TC0 from hring[HSEL]
#define CVT_CHUNK(HSEL, TC0)                                                 \
        {                                                                    \
            const float4 hv4 = *(const float4*)&hring[HSEL][u_r][dc];        \
            float xr[4] = {hv4.x, hv4.y, hv4.z, hv4.w};                      \
            u16 rh[4], rl[4];                                                \
            _Pragma("unroll")                                                \
            for (int i = 0; i < 4; ++i) {                                    \
                rh[i] = f2bf_rne(xr[i]);                                     \
                rl[i] = f2bf_rne(xr[i] - bf2f(rh[i]));                       \
            }                                                                \
            ushort4 rhv = {rh[0], rh[1], rh[2], rh[3]};                      \
            ushort4 rlv = {rl[0], rl[1], rl[2], rl[3]};                      \
            *(ushort4*)&hhb[(size_t)((TC0) + u_r) * DD + dc] = rhv;          \
            *(ushort4*)&hlb[(size_t)((TC0) + u_r) * DD + dc] = rlv;          \
            u16 ch[4], cl[4];                                                \
            _Pragma("unroll")                                                \
            for (int j = 0; j < 4; ++j) {                                    \
                float x = hring[HSEL][ug + j][d_c];                          \
                ch[j] = f2bf_rne(x);                                         \
                cl[j] = f2bf_rne(x - bf2f(ch[j]));                           \
            }                                                                \
            ushort4 chv = {ch[0], ch[1], ch[2], ch[3]};                      \
            ushort4 clv = {cl[0], cl[1], cl[2], cl[3]};                      \
            *(ushort4*)&thb[(size_t)d_c * TT + (TC0) + ug] = chv;            \
            *(ushort4*)&tlb[(size_t)d_c * TT + (TC0) + ug] = clv;            \
        }

        {
            int id0 = idsb[0]; if ((unsigned)id0 >= VOCABN) id0 = 0;
            float ec = emb[id0 * DD + dd];
#pragma unroll
            for (int u = 0; u < UU; ++u) {
                float en = 0.f;
                if (u + 1 < UU) {
                    int idn = idsb[u + 1]; if ((unsigned)idn >= VOCABN) idn = 0;
                    en = emb[idn * DD + dd];
                }
                PROD_TOKEN(0, u, ec)
                ec = en;
            }
        }
        __syncthreads();
        int sel = 0;
        for (int t0 = 0; t0 < TT; t0 += UU) {
            if (t0 + UU < TT) {
                const int s = sel ^ 1;
                int id0 = idsb[t0 + UU]; if ((unsigned)id0 >= VOCABN) id0 = 0;
                float ec = emb[id0 * DD + dd];
#pragma unroll
                for (int u = 0; u < UU; ++u) {
                    float en = 0.f;
                    if (u + 1 < UU) {
                        int tn = t0 + UU + u + 1;
                        if (tn > TT - 1) tn = TT - 1;
                        int idn = idsb[tn]; if ((unsigned)idn >= VOCABN) idn = 0;
                        en = emb[idn * DD + dd];
                    }
                    PROD_TOKEN(s, u, ec)
                    ec = en;
                }
            }
            // cvt previous chunk (consumer wrote hring[(t0/UU-1)&1] before
            // the last barrier)
            if (t0) CVT_CHUNK((t0 / UU - 1) & 1, t0 - UU)
            __syncthreads();
            sel ^= 1;
        }
        // epilogue: convert the final chunk (written before the last barrier)
        CVT_CHUNK(1, TT - UU)
#undef PROD_TOKEN
#undef CVT_CHUNK
        return;
    }

    // ---------------- consumer: R19-exact scan + pk_fma dots ----------------
    const int d = l & 31;
    const bool hi = l >= 32;
    const int ga = (hi ? 32 : 0) + d;
    const int gb = (hi ? 96 : 64) + d;
    floatx2 rkp[DD];
#pragma unroll
    for (int k = 0; k < DD; ++k)
        rkp[k] = (floatx2){rk[k * GG + ga], rk[k * GG + gb]};
    float* hb = hout + (size_t)b * TT * DD;

    float h = 0.0f, c = 0.0f;
    float hreg[UU];
    __syncthreads();   // matches producer prologue barrier
    int sel = 0;
    for (int t0 = 0; t0 < TT; t0 += UU) {
        // flush previous chunk's h first: stores retire under this chunk's
        // compute, so the chunk-end barrier's vmcnt(0) drain is free.
        if (t0 && !hi) {
#pragma unroll
            for (int u = 0; u < UU; ++u) hb[(size_t)(t0 - UU + u) * DD + d] = hreg[u];
        }
        float pa[UU], pb[UU];
#pragma unroll
        for (int u = 0; u < UU; ++u) {
            pa[u] = ring[sel][u][ga];
            pb[u] = ring[sel][u][gb];
        }
#pragma unroll
        for (int u = 0; u < UU; ++u) {
            floatx2 x0 = {pa[u], pb[u]};
            floatx2 x1 = {0.f, 0.f}, x2 = {0.f, 0.f}, x3 = {0.f, 0.f};
#pragma unroll
            for (int k = 0; k < DD; k += 4) {
                float h0 = readlane_f(h, k);
                float h1 = readlane_f(h, k + 1);
                float h2 = readlane_f(h, k + 2);
                float h3 = readlane_f(h, k + 3);
                x0 = fma2(h0, rkp[k],     x0);
                x1 = fma2(h1, rkp[k + 1], x1);
                x2 = fma2(h2, rkp[k + 2], x2);
                x3 = fma2(h3, rkp[k + 3], x3);
            }
            floatx2 zf = (x0 + x1) + (x2 + x3);
            float za = zf.x, zb = zf.y;
            float a = fsig(za);                       // sig(i) lo / sig(f) hi
            float zbm = hi ? zb : 2.0f * zb;
            float s2 = fsig(zbm);
            float bv = hi ? s2 : 2.0f * s2 - 1.0f;    // sig(o) hi / tanh(g) lo
            // lane<32 <-> lane+32 exchange via v_permlane32_swap_b32 (VALU).
            auto r1 = __builtin_amdgcn_permlane32_swap(
                __float_as_int(bv), __float_as_int(a), false, false);
            auto r2 = __builtin_amdgcn_permlane32_swap(
                __float_as_int(a), __float_as_int(bv), false, false);
            float fg = __int_as_float(r1[0]);
            float og = __int_as_float(r2[0]);
            c = fmaf(fg, c, a * bv);
            float tc = 2.0f * fsig(2.0f * c) - 1.0f;
            h = og * tc;
            hreg[u] = h;
            if (!hi) hring[sel][u][d] = h;   // h ring for producer-side cvt
        }
        __syncthreads();
        sel ^= 1;
    }
    if (!hi) {
#pragma unroll
        for (int u = 0; u < UU; ++u) hb[(size_t)(TT - UU + u) * DD + d] = hreg[u];
    }
}

// ---------------------------------------------------------------------------
// Kernel 3: attention — R25 math (4 q-tiles/wave, verified). R26 delta: the
// epilogue writes ctx TRANSPOSED as bf16 hi/lo (cth/ctl, [d][t] like th/tl)
// instead of row-major f32 — same byte volume, MFMA-ready for ymlp.
// ---------------------------------------------------------------------------
__global__ __launch_bounds__(256, 1) void k_attn(const u16* __restrict__ hh,
                                                 const u16* __restrict__ hl,
                                                 const u16* __restrict__ th,
                                                 const u16* __restrict__ tl,
                                                 u16* __restrict__ cth,
                                                 u16* __restrict__ ctl) {
    __shared__ u16 plds[4][4][2][16 * 40];   // [wave][tile][dbuf][16x40]
    const int tid = threadIdx.x;
    const int w = tid >> 6;
    const int l = tid & 63;
    const int m = l & 15;
    const int g = l >> 4;
    const int b = blockIdx.x & 63;              // XCD swizzle: XCD = b % 8
    const int qt = (blockIdx.x >> 6) * 4 + w;   // 64-row wave tile, 0..15
    const int q0 = qt * 64;
    const size_t rb = (size_t)b * TT * DD;
    const size_t tb = (size_t)b * DD * TT;

    const short8 Qh0 = *(const short8*)&hh[rb + (size_t)(q0 + m) * DD + g * 8];
    const short8 Ql0 = *(const short8*)&hl[rb + (size_t)(q0 + m) * DD + g * 8];
    const short8 Qh1 = *(const short8*)&hh[rb + (size_t)(q0 + 16 + m) * DD + g * 8];
    const short8 Ql1 = *(const short8*)&hl[rb + (size_t)(q0 + 16 + m) * DD + g * 8];
    const short8 Qh2 = *(const short8*)&hh[rb + (size_t)(q0 + 32 + m) * DD + g * 8];
    const short8 Ql2 = *(const short8*)&hl[rb + (size_t)(q0 + 32 + m) * DD + g * 8];
    const short8 Qh3 = *(const short8*)&hh[rb + (size_t)(q0 + 48 + m) * DD + g * 8];
    const short8 Ql3 = *(const short8*)&hl[rb + (size_t)(q0 + 48 + m) * DD + g * 8];
    short8 ONES;
#pragma unroll
    for (int j = 0; j < 8; ++j) ONES[j] = (short)0x3F80;

    floatx4 c0 = {0.f, 0.f, 0.f, 0.f}, c1 = {0.f, 0.f, 0.f, 0.f};
    floatx4 c2 = {0.f, 0.f, 0.f, 0.f}, c3 = {0.f, 0.f, 0.f, 0.f};
    floatx4 c4 = {0.f, 0.f, 0.f, 0.f}, c5 = {0.f, 0.f, 0.f, 0.f};
    floatx4 c6 = {0.f, 0.f, 0.f, 0.f}, c7 = {0.f, 0.f, 0.f, 0.f};
    floatx4 la0 = {0.f, 0.f, 0.f, 0.f}, la1 = {0.f, 0.f, 0.f, 0.f};
    floatx4 la2 = {0.f, 0.f, 0.f, 0.f}, la3 = {0.f, 0.f, 0.f, 0.f};

#define S_BLOCK(QH, QL, KH_A, KL_A, KH_B, KL_B, SA, SB)                       \
    SA = __builtin_amdgcn_mfma_f32_16x16x32_bf16(QH, KH_A, SA, 0, 0, 0);      \
    SA = __builtin_amdgcn_mfma_f32_16x16x32_bf16(QH, KL_A, SA, 0, 0, 0);      \
    SA = __builtin_amdgcn_mfma_f32_16x16x32_bf16(QL, KH_A, SA, 0, 0, 0);      \
    SB = __builtin_amdgcn_mfma_f32_16x16x32_bf16(QH, KH_B, SB, 0, 0, 0);      \
    SB = __builtin_amdgcn_mfma_f32_16x16x32_bf16(QH, KL_B, SB, 0, 0, 0);      \
    SB = __builtin_amdgcn_mfma_f32_16x16x32_bf16(QL, KH_B, SB, 0, 0, 0);

#define EXP_STORE(SA, SB, TILE, SLOT)                                         \
    {                                                                         \
        u16* lp = plds[w][TILE][SLOT];                                        \
        _Pragma("unroll")                                                     \
        for (int r = 0; r < 4; ++r) {                                         \
            lp[(g * 4 + r) * 40 + m]      = f2bf_rne(__expf(SA[r]));          \
            lp[(g * 4 + r) * 40 + 16 + m] = f2bf_rne(__expf(SB[r]));          \
        }                                                                     \
    }

    // ---- kp = 0: S + exp + write slot0 for all four tiles; no PV yet ----
    {
        short8 KhA = *(const short8*)&hh[rb + (size_t)(m) * DD + g * 8];
        short8 KlA = *(const short8*)&hl[rb + (size_t)(m) * DD + g * 8];
        short8 KhB = *(const short8*)&hh[rb + (size_t)(16 + m) * DD + g * 8];
        short8 KlB = *(const short8*)&hl[rb + (size_t)(16 + m) * DD + g * 8];
        floatx4 sA = {0.f, 0.f, 0.f, 0.f}, sB = {0.f, 0.f, 0.f, 0.f};
        floatx4 tA = {0.f, 0.f, 0.f, 0.f}, tB = {0.f, 0.f, 0.f, 0.f};
        floatx4 uA = {0.f, 0.f, 0.f, 0.f}, uB = {0.f, 0.f, 0.f, 0.f};
        floatx4 vA = {0.f, 0.f, 0.f, 0.f}, vB = {0.f, 0.f, 0.f, 0.f};
        S_BLOCK(Qh0, Ql0, KhA, KlA, KhB, KlB, sA, sB)
        S_BLOCK(Qh1, Ql1, KhA, KlA, KhB, KlB, tA, tB)
        S_BLOCK(Qh2, Ql2, KhA, KlA, KhB, KlB, uA, uB)
        S_BLOCK(Qh3, Ql3, KhA, KlA, KhB, KlB, vA, vB)
        EXP_STORE(sA, sB, 0, 0)
        EXP_STORE(tA, tB, 1, 0)
        EXP_STORE(uA, uB, 2, 0)
        EXP_STORE(vA, vB, 3, 0)
    }
    // preload V_0 (used at kp=1) and K_1 — shared by all four tiles
    short8 Vh0 = *(const short8*)&th[tb + (size_t)m * TT + g * 8];
    short8 Vl0 = *(const short8*)&tl[tb + (size_t)m * TT + g * 8];
    short8 Vh1 = *(const short8*)&th[tb + (size_t)(16 + m) * TT + g * 8];
    short8 Vl1 = *(const short8*)&tl[tb + (size_t)(16 + m) * TT + g * 8];
    short8 KhA = *(const short8*)&hh[rb + (size_t)(32 + m) * DD + g * 8];
    short8 KlA = *(const short8*)&hl[rb + (size_t)(32 + m) * DD + g * 8];
    short8 KhB = *(const short8*)&hh[rb + (size_t)(48 + m) * DD + g * 8];
    short8 KlB = *(const short8*)&hl[rb + (size_t)(48 + m) * DD + g * 8];

#pragma unroll 1
    for (int kp = 1; kp < 32; ++kp) {
        const int knK = (kp < 31) ? (kp + 1) * 32 : 0;
        const int knV = kp * 32;
        short8 nKhA = *(const short8*)&hh[rb + (size_t)(knK + m) * DD + g * 8];
        short8 nKlA = *(const short8*)&hl[rb + (size_t)(knK + m) * DD + g * 8];
        short8 nKhB = *(const short8*)&hh[rb + (size_t)(knK + 16 + m) * DD + g * 8];
        short8 nKlB = *(const short8*)&hl[rb + (size_t)(knK + 16 + m) * DD + g * 8];
        short8 nVh0 = *(const short8*)&th[tb + (size_t)m * TT + knV + g * 8];
        short8 nVl0 = *(const short8*)&tl[tb + (size_t)m * TT + knV + g * 8];
        short8 nVh1 = *(const short8*)&th[tb + (size_t)(16 + m) * TT + knV + g * 8];
        short8 nVl1 = *(const short8*)&tl[tb + (size_t)(16 + m) * TT + knV + g * 8];

        floatx4 sA = {0.f, 0.f, 0.f, 0.f}, sB = {0.f, 0.f, 0.f, 0.f};
        floatx4 tA = {0.f, 0.f, 0.f, 0.f}, tB = {0.f, 0.f, 0.f, 0.f};
        floatx4 uA = {0.f, 0.f, 0.f, 0.f}, uB = {0.f, 0.f, 0.f, 0.f};
        floatx4 vA = {0.f, 0.f, 0.f, 0.f}, vB = {0.f, 0.f, 0.f, 0.f};
        S_BLOCK(Qh0, Ql0, KhA, KlA, KhB, KlB, sA, sB)
        S_BLOCK(Qh1, Ql1, KhA, KlA, KhB, KlB, tA, tB)
        S_BLOCK(Qh2, Ql2, KhA, KlA, KhB, KlB, uA, uB)
        S_BLOCK(Qh3, Ql3, KhA, KlA, KhB, KlB, vA, vB)

        const int ps = (kp - 1) & 1;
        const short8 P0 = *(const short8*)&plds[w][0][ps][m * 40 + g * 8];
        const short8 P1 = *(const short8*)&plds[w][1][ps][m * 40 + g * 8];
        const short8 P2 = *(const short8*)&plds[w][2][ps][m * 40 + g * 8];
        const short8 P3 = *(const short8*)&plds[w][3][ps][m * 40 + g * 8];

        c0  = __builtin_amdgcn_mfma_f32_16x16x32_bf16(P0, Vh0, c0, 0, 0, 0);
        c0  = __builtin_amdgcn_mfma_f32_16x16x32_bf16(P0, Vl0, c0, 0, 0, 0);
        c1  = __builtin_amdgcn_mfma_f32_16x16x32_bf16(P0, Vh1, c1, 0, 0, 0);
        c1  = __builtin_amdgcn_mfma_f32_16x16x32_bf16(P0, Vl1, c1, 0, 0, 0);
        la0 = __builtin_amdgcn_mfma_f32_16x16x32_bf16(P0, ONES, la0, 0, 0, 0);
        c2  = __builtin_amdgcn_mfma_f32_16x16x32_bf16(P1, Vh0, c2, 0, 0, 0);
        c2  = __builtin_amdgcn_mfma_f32_16x16x32_bf16(P1, Vl0, c2, 0, 0, 0);
        c3  = __builtin_amdgcn_mfma_f32_16x16x32_bf16(P1, Vh1, c3, 0, 0, 0);
        c3  = __builtin_amdgcn_mfma_f32_16x16x32_bf16(P1, Vl1, c3, 0, 0, 0);
        la1 = __builtin_amdgcn_mfma_f32_16x16x32_bf16(P1, ONES, la1, 0, 0, 0);
        c4  = __builtin_amdgcn_mfma_f32_16x16x32_bf16(P2, Vh0, c4, 0, 0, 0);
        c4  = __builtin_amdgcn_mfma_f32_16x16x32_bf16(P2, Vl0, c4, 0, 0, 0);
        c5  = __builtin_amdgcn_mfma_f32_16x16x32_bf16(P2, Vh1, c5, 0, 0, 0);
        c5  = __builtin_amdgcn_mfma_f32_16x16x32_bf16(P2, Vl1, c5, 0, 0, 0);
        la2 = __builtin_amdgcn_mfma_f32_16x16x32_bf16(P2, ONES, la2, 0, 0, 0);
        c6  = __builtin_amdgcn_mfma_f32_16x16x32_bf16(P3, Vh0, c6, 0, 0, 0);
        c6  = __builtin_amdgcn_mfma_f32_16x16x32_bf16(P3, Vl0, c6, 0, 0, 0);
        c7  = __builtin_amdgcn_mfma_f32_16x16x32_bf16(P3, Vh1, c7, 0, 0, 0);
        c7  = __builtin_amdgcn_mfma_f32_16x16x32_bf16(P3, Vl1, c7, 0, 0, 0);
        la3 = __builtin_amdgcn_mfma_f32_16x16x32_bf16(P3, ONES, la3, 0, 0, 0);

        EXP_STORE(sA, sB, 0, kp & 1)
        EXP_STORE(tA, tB, 1, kp & 1)
        EXP_STORE(uA, uB, 2, kp & 1)
        EXP_STORE(vA, vB, 3, kp & 1)

        KhA = nKhA; KlA = nKlA; KhB = nKhB; KlB = nKlB;
        Vh0 = nVh0; Vl0 = nVl0; Vh1 = nVh1; Vl1 = nVl1;
    }
    // epilogue: PV of kp=31 for all four tiles
    {
        const short8 P0 = *(const short8*)&plds[w][0][1][m * 40 + g * 8];
        const short8 P1 = *(const short8*)&plds[w][1][1][m * 40 + g * 8];
        const short8 P2 = *(const short8*)&plds[w][2][1][m * 40 + g * 8];
        const short8 P3 = *(const short8*)&plds[w][3][1][m * 40 + g * 8];
        c0  = __builtin_amdgcn_mfma_f32_16x16x32_bf16(P0, Vh0, c0, 0, 0, 0);
        c0  = __builtin_amdgcn_mfma_f32_16x16x32_bf16(P0, Vl0, c0, 0, 0, 0);
        c1  = __builtin_amdgcn_mfma_f32_16x16x32_bf16(P0, Vh1, c1, 0, 0, 0);
        c1  = __builtin_amdgcn_mfma_f32_16x16x32_bf16(P0, Vl1, c1, 0, 0, 0);
        la0 = __builtin_amdgcn_mfma_f32_16x16x32_bf16(P0, ONES, la0, 0, 0, 0);
        c2  = __builtin_amdgcn_mfma_f32_16x16x32_bf16(P1, Vh0, c2, 0, 0, 0);
        c2  = __builtin_amdgcn_mfma_f32_16x16x32_bf16(P1, Vl0, c2, 0, 0, 0);
        c3  = __builtin_amdgcn_mfma_f32_16x16x32_bf16(P1, Vh1, c3, 0, 0, 0);
        c3  = __builtin_amdgcn_mfma_f32_16x16x32_bf16(P1, Vl1, c3, 0, 0, 0);
        la1 = __builtin_amdgcn_mfma_f32_16x16x32_bf16(P1, ONES, la1, 0, 0, 0);
        c4  = __builtin_amdgcn_mfma_f32_16x16x32_bf16(P2, Vh0, c4, 0, 0, 0);
        c4  = __builtin_amdgcn_mfma_f32_16x16x32_bf16(P2, Vl0, c4, 0, 0, 0);
        c5  = __builtin_amdgcn_mfma_f32_16x16x32_bf16(P2, Vh1, c5, 0, 0, 0);
        c5  = __builtin_amdgcn_mfma_f32_16x16x32_bf16(P2, Vl1, c5, 0, 0, 0);
        la2 = __builtin_amdgcn_mfma_f32_16x16x32_bf16(P2, ONES, la2, 0, 0, 0);
        c6  = __builtin_amdgcn_mfma_f32_16x16x32_bf16(P3, Vh0, c6, 0, 0, 0);
        c6  = __builtin_amdgcn_mfma_f32_16x16x32_bf16(P3, Vl0, c6, 0, 0, 0);
        c7  = __builtin_amdgcn_mfma_f32_16x16x32_bf16(P3, Vh1, c7, 0, 0, 0);
        c7  = __builtin_amdgcn_mfma_f32_16x16x32_bf16(P3, Vl1, c7, 0, 0, 0);
        la3 = __builtin_amdgcn_mfma_f32_16x16x32_bf16(P3, ONES, la3, 0, 0, 0);
    }
#undef S_BLOCK
#undef EXP_STORE
    // R26 epilogue: transposed bf16 hi/lo ctx stores (cth/ctl, [d][t]).
#define CTX_STORE(VAL, DROW, TCOL)                                            \
    {                                                                         \
        float v_ = (VAL);                                                     \
        u16 h_ = f2bf_rne(v_);                                                \
        cth[tb + (size_t)(DROW) * TT + (TCOL)] = h_;                          \
        ctl[tb + (size_t)(DROW) * TT + (TCOL)] = f2bf_rne(v_ - bf2f(h_));     \
    }
#pragma unroll
    for (int r = 0; r < 4; ++r) {
        float li0 = __builtin_amdgcn_rcpf(la0[r]);
        float li1 = __builtin_amdgcn_rcpf(la1[r]);
        float li2 = __builtin_amdgcn_rcpf(la2[r]);
        float li3 = __builtin_amdgcn_rcpf(la3[r]);
        const int ta = q0 + g * 4 + r;
        const int tbr = q0 + 16 + g * 4 + r;
        const int tc = q0 + 32 + g * 4 + r;
        const int td = q0 + 48 + g * 4 + r;
        CTX_STORE(c0[r] * li0, m, ta)
        CTX_STORE(c1[r] * li0, 16 + m, ta)
        CTX_STORE(c2[r] * li1, m, tbr)
        CTX_STORE(c3[r] * li1, 16 + m, tbr)
        CTX_STORE(c4[r] * li2, m, tc)
        CTX_STORE(c5[r] * li2, 16 + m, tc)
        CTX_STORE(c6[r] * li3, m, td)
        CTX_STORE(c7[r] * li3, 16 + m, td)
    }
#undef CTX_STORE
}

// ---------------------------------------------------------------------------
// Kernel 4: ymlp — R26: MFMA rewrite. y[d][e] = sum_t ctx[t][d] h[t][e] is a
// 32x32xK=1024 matmul; cth/ctl and th/tl are both [d][t]-layout bf16 hi/lo,
// exactly the A/B fragment layouts of mfma_f32_16x16x32_bf16 (A row=l&15,
// B col=l&15, contraction octet=(l>>4)*8 — same pattern as attn's PV).
// 4 waves each do K=256 partials (3-term hi/lo split: AhBh+AhBl+AlBh, the
// same approximation attn uses), LDS-reduce, then the exact W1/W2 tail.
// Replaces a 26k-cycle scalar-FMA loop + 16MB f32 staging.
// ---------------------------------------------------------------------------
__global__ __launch_bounds__(256) void k_ymlp(const u16* __restrict__ cth,
                                              const u16* __restrict__ ctl,
                                              const u16* __restrict__ th,
                                              const u16* __restrict__ tl,
                                              const float* __restrict__ W1,
                                              const float* __restrict__ b1,
                                              const float* __restrict__ W2,
                                              const float* __restrict__ b2,
                                              float* __restrict__ out) {
    const int b = blockIdx.x;
    const int tid = threadIdx.x;
    const int w = tid >> 6;
    const int l = tid & 63;
    const int m = l & 15;
    const int g = l >> 4;
    const size_t tb = (size_t)b * DD * TT;
    const int k0 = w * (TT / 4);

    floatx4 y00 = {0.f, 0.f, 0.f, 0.f}, y01 = {0.f, 0.f, 0.f, 0.f};
    floatx4 y10 = {0.f, 0.f, 0.f, 0.f}, y11 = {0.f, 0.f, 0.f, 0.f};
#pragma unroll 2
    for (int ks = 0; ks < TT / 4; ks += 32) {
        const size_t kk = (size_t)(k0 + ks + g * 8);
        short8 A0h = *(const short8*)&cth[tb + (size_t)m * TT + kk];
        short8 A0l = *(const short8*)&ctl[tb + (size_t)m * TT + kk];
        short8 A1h = *(const short8*)&cth[tb + (size_t)(16 + m) * TT + kk];
        short8 A1l = *(const short8*)&ctl[tb + (size_t)(16 + m) * TT + kk];
        short8 B0h = *(const short8*)&th[tb + (size_t)m * TT + kk];
        short8 B0l = *(const short8*)&tl[tb + (size_t)m * TT + kk];
        short8 B1h = *(const short8*)&th[tb + (size_t)(16 + m) * TT + kk];
        short8 B1l = *(const short8*)&tl[tb + (size_t)(16 + m) * TT + kk];
        y00 = __builtin_amdgcn_mfma_f32_16x16x32_bf16(A0h, B0h, y00, 0, 0, 0);
        y00 = __builtin_amdgcn_mfma_f32_16x16x32_bf16(A0h, B0l, y00, 0, 0, 0);
        y00 = __builtin_amdgcn_mfma_f32_16x16x32_bf16(A0l, B0h, y00, 0, 0, 0);
        y01 = __builtin_amdgcn_mfma_f32_16x16x32_bf16(A0h, B1h, y01, 0, 0, 0);
        y01 = __builtin_amdgcn_mfma_f32_16x16x32_bf16(A0h, B1l, y01, 0, 0, 0);
        y01 = __builtin_amdgcn_mfma_f32_16x16x32_bf16(A0l, B1h, y01, 0, 0, 0);
        y10 = __builtin_amdgcn_mfma_f32_16x16x32_bf16(A1h, B0h, y10, 0, 0, 0);
        y10 = __builtin_amdgcn_mfma_f32_16x16x32_bf16(A1h, B0l, y10, 0, 0, 0);
        y10 = __builtin_amdgcn_mfma_f32_16x16x32_bf16(A1l, B0h, y10, 0, 0, 0);
        y11 = __builtin_amdgcn_mfma_f32_16x16x32_bf16(A1h, B1h, y11, 0, 0, 0);
        y11 = __builtin_amdgcn_mfma_f32_16x16x32_bf16(A1h, B1l, y11, 0, 0, 0);
        y11 = __builtin_amdgcn_mfma_f32_16x16x32_bf16(A1l, B1h, y11, 0, 0, 0);
    }
    __shared__ float ysp[4][DD][DD];
#pragma unroll
    for (int r = 0; r < 4; ++r) {
        // C/D layout: col = l&15, row = (l>>4)*4 + r
        ysp[w][g * 4 + r][m]           = y00[r];
        ysp[w][g * 4 + r][16 + m]      = y01[r];
        ysp[w][16 + g * 4 + r][m]      = y10[r];
        ysp[w][16 + g * 4 + r][16 + m] = y11[r];
    }
    __syncthreads();
    const int e = tid & 31;
    const int d4 = (tid >> 5) * 4;
    __shared__ float ys[DD][DD];
#pragma unroll
    for (int r = 0; r < 4; ++r)
        ys[d4 + r][e] = (ysp[0][d4 + r][e] + ysp[1][d4 + r][e])
                      + (ysp[2][d4 + r][e] + ysp[3][d4 + r][e]);
    __syncthreads();
    __shared__ float yr[DD][33];
#pragma unroll
    for (int r = 0; r < 4; ++r) {
        float v = b1[e];
#pragma unroll
        for (int ee = 0; ee < DD; ++ee) v += ys[d4 + r][ee] * W1[ee * DD + e];
        yr[d4 + r][e] = fmaxf(v, 0.0f);
    }
    __syncthreads();
    if (tid < DD) {
        float v = b2[0];
#pragma unroll
        for (int ee = 0; ee < DD; ++ee) v += yr[tid][ee] * W2[ee];
        out[b * DD + tid] = 1.0f / (1.0f + expf(-v));
    }
}

// ---------------------------------------------------------------------------
extern "C" void kernel_launch(void* const* d_in, const int* in_sizes, int n_in,
                              void* d_out, int out_size, void* d_ws, size_t ws_size,
                              hipStream_t stream) {
    const int* ids   = (const int*)d_in[0];
    const float* emb = (const float*)d_in[1];
    const float* kl  = (const float*)d_in[2];
    const float* rk  = (const float*)d_in[3];
    const float* bl  = (const float*)d_in[4];
    const float* W1  = (const float*)d_in[5];
    const float* b1  = (const float*)d_in[6];
    const float* W2  = (const float*)d_in[7];
    const float* b2  = (const float*)d_in[8];
    float* out = (float*)d_out;

    char* ws = (char*)d_ws;
    const size_t H_ELEMS = (size_t)BB * TT * DD;   // 2,097,152
    u16* hh   = (u16*)ws;
    u16* hl   = (u16*)(ws + H_ELEMS * 2);
    u16* th   = (u16*)(ws + H_ELEMS * 4);
    u16* tl   = (u16*)(ws + H_ELEMS * 6);
    float* h  = (float*)(ws + H_ELEMS * 8);
    u16* cth  = (u16*)(ws + H_ELEMS * 8 + H_ELEMS * 4);
    u16* ctl  = (u16*)(ws + H_ELEMS * 8 + H_ELEMS * 4 + H_ELEMS * 2);
    int* list = (int*)(ws + H_ELEMS * 8 + H_ELEMS * 8);

    k_lstm_scan<<<BB + 1, 128, 0, stream>>>(ids, emb, kl, bl, rk, h,
                                            hh, hl, th, tl, list, out + BB * DD);
    k_attn<<<BB * 4, 256, 0, stream>>>(hh, hl, th, tl, cth, ctl);
    k_ymlp<<<BB, 256, 0, stream>>>(cth, ctl, th, tl, W1, b1, W2, b2, out);
}

// Round 10
// 358.122 us; speedup vs baseline: 1.5359x; 1.0233x over previous
//
#include <hip/hip_runtime.h>
#include <math.h>

#define BB 64
#define TT 1024
#define DD 32
#define GG 128   // 4*D
#define VOCABN 10000
#define QLEN 100

typedef short short8 __attribute__((ext_vector_type(8)));   // 8 bf16 in 4 VGPRs
typedef float floatx4 __attribute__((ext_vector_type(4)));
typedef float floatx2 __attribute__((ext_vector_type(2)));
typedef unsigned short u16;

__device__ __forceinline__ float fsig(float x) {
    return __builtin_amdgcn_rcpf(1.0f + __expf(-x));
}
__device__ __forceinline__ float readlane_f(float v, int l) {
    return __int_as_float(__builtin_amdgcn_readlane(__float_as_int(v), l));
}
__device__ __forceinline__ u16 f2bf_rne(float x) {
    unsigned u = __float_as_uint(x);
    u += 0x7FFF + ((u >> 16) & 1);
    return (u16)(u >> 16);
}
__device__ __forceinline__ float bf2f(u16 s) {
    return __uint_as_float(((unsigned)s) << 16);
}
// packed fma: one v_pk_fma_f32 for the {a,b}-gate pair. IEEE fma per half ->
// bit-exact vs two fmaf.
__device__ __forceinline__ floatx2 fma2(float s, floatx2 w, floatx2 acc) {
    return __builtin_elementwise_fma((floatx2){s, s}, w, acc);
}

// ---------------------------------------------------------------------------
// Kernel 1: LSTM scan — R21-EXACT (measured 241-257 µs, VGPR 132). DO NOT
// TOUCH: R23/R24 showed any reshape loses the 132-VGPR allocation and spills
// the weight arrays onto the serial chain. pk_fma dots + permlane32_swap +
// cvt fused into producer slack. Queue fused as blk 64 wave 0.
// ---------------------------------------------------------------------------
#define UU 8
__global__
__attribute__((amdgpu_flat_work_group_size(128, 128)))
__attribute__((amdgpu_waves_per_eu(1, 1)))
void k_lstm_scan(const int* __restrict__ ids,
                 const float* __restrict__ emb,
                 const float* __restrict__ klstm,
                 const float* __restrict__ bias,
                 const float* __restrict__ rk,
                 float* __restrict__ hout,
                 u16* __restrict__ hh, u16* __restrict__ hl,
                 u16* __restrict__ th, u16* __restrict__ tl,
                 int* __restrict__ list,
                 float* __restrict__ outq) {
    const int b = blockIdx.x;
    const int tid = threadIdx.x;
    const int wv = tid >> 6;   // wave 0 consumer / wave 1 producer+cvt
    const int l = tid & 63;
    if (b >= BB) {
        if (wv != 0) return;
        // ---- fused zero-index queue (single wave, no barriers) ----
        const int4* v4 = (const int4*)ids;
        const int C4 = (BB * TT) / 4 / 64;
        const int b4 = l * C4;
        int cnt = 0;
#pragma unroll 4
        for (int i = 0; i < C4; ++i) {
            int4 v = v4[b4 + i];
            cnt += (v.x == 0 || (unsigned)v.x >= VOCABN);
            cnt += (v.y == 0 || (unsigned)v.y >= VOCABN);
            cnt += (v.z == 0 || (unsigned)v.z >= VOCABN);
            cnt += (v.w == 0 || (unsigned)v.w >= VOCABN);
        }
        int scan = cnt;
#pragma unroll
        for (int o = 1; o < 64; o <<= 1) {
            int nn = __shfl_up(scan, o);
            if (l >= o) scan += nn;
        }
        const int total = __shfl(scan, 63);
        int off = scan - cnt;
        const int base = l * (C4 * 4);
#pragma unroll 4
        for (int i = 0; i < C4; ++i) {
            int4 v = v4[b4 + i];
            if (v.x == 0 || (unsigned)v.x >= VOCABN) list[off++] = base + 4 * i;
            if (v.y == 0 || (unsigned)v.y >= VOCABN) list[off++] = base + 4 * i + 1;
            if (v.z == 0 || (unsigned)v.z >= VOCABN) list[off++] = base + 4 * i + 2;
            if (v.w == 0 || (unsigned)v.w >= VOCABN) list[off++] = base + 4 * i + 3;
        }
        __threadfence();
        const int Kc = total < QLEN ? total : QLEN;
        for (int t = l; t < QLEN; t += 64) {
            float ii = -1.0f, jj = -1.0f;
            if (t >= QLEN - Kc) {
                int pos = list[total - QLEN + t];
                ii = (float)(pos >> 10);
                jj = (float)(pos & (TT - 1));
            }
            outq[2 * t] = ii;
            outq[2 * t + 1] = jj;
        }
        return;
    }

    __shared__ float ring[2][UU][GG];                    // 8 KB xg ring
    __shared__ __align__(16) float hring[2][UU][DD];     // 2 KB h ring (cvt)
    const int* idsb = ids + b * TT;

    if (wv == 1) {
        // ---------- producer: xg 8 tokens ahead + cvt of chunk-1 -----------
        const int ja = l, jb = l + 64;
        floatx2 kp[DD];
#pragma unroll
        for (int d2 = 0; d2 < DD; ++d2)
            kp[d2] = (floatx2){klstm[d2 * GG + ja], klstm[d2 * GG + jb]};
        const floatx2 bj = (floatx2){bias[ja], bias[jb]};
        const int dd = l & 31;
        // cvt lane mappings
        const int u_r = l >> 3, dc = (l & 7) * 4;        // row side: 8B u16 runs
        const int d_c = l & 31, ug = (l >> 5) * 4;       // col side: 4 consecutive t
        u16* hhb = hh + (size_t)b * TT * DD;
        u16* hlb = hl + (size_t)b * TT * DD;
        u16* thb = th + (size_t)b * DD * TT;
        u16* tlb = tl + (size_t)b * DD * TT;

#define PROD_TOKEN(SEL, U, EV)                                               \
        {                                                                    \
            floatx2 z0 = bj;                                                 \
            floatx2 z1 = {0.f, 0.f}, z2 = {0.f, 0.f}, z3 = {0.f, 0.f};       \
            _Pragma("unroll")                                                \
            for (int k = 0; k < DD; k += 4) {                                \
                float e0 = readlane_f(EV, k);                                \
                float e1 = readlane_f(EV, k + 1);                            \
                float e2 = readlane_f(EV, k + 2);                            \
                float e3 = readlane_f(EV, k + 3);                            \
                z0 = fma2(e0, kp[k], z0);                                    \
                z1 = fma2(e1, kp[k + 1], z1);                                \
                z2 = fma2(e2, kp[k + 2], z2);                                \
                z3 = fma2(e3, kp[k + 3], z3);                                \
            }                                                                \
            floatx2 zf = (z0 + z1) + (z2 + z3);                              \
            ring[SEL][U][ja] = zf.x;                                         \
            ring[SEL][U][jb] = zf.y;                                         \
        }

        // convert chunk starting at token TC0 from hring[HSEL]
#define CVT_CHUNK(HSEL, TC0)                                                 \
        {                                                                    \
            const float4 hv4 = *(const float4*)&hring[HSEL][u_r][dc];        \
            float xr[4] = {hv4.x, hv4.y, hv4.z, hv4.w};                      \
            u16 rh[4], rl[4];                                                \
            _Pragma("unroll")                                                \
            for (int i = 0; i < 4; ++i) {                                    \
                rh[i] = f2bf_rne(xr[i]);                                     \
                rl[i] = f2bf_rne(xr[i] - bf2f(rh[i]));                       \
            }                                                                \
            ushort4 rhv = {rh[0], rh[1], rh[2], rh[3]};                      \
            ushort4 rlv = {rl[0], rl[1], rl[2], rl[3]};                      \
            *(ushort4*)&hhb[(size_t)((TC0) + u_r) * DD + dc] = rhv;          \
            *(ushort4*)&hlb[(size_t)((TC0) + u_r) * DD + dc] = rlv;          \
            u16 ch[4], cl[4];                                                \
            _Pragma("unroll")                                                \
            for (int j = 0; j < 4; ++j) {                                    \
                float x = hring[HSEL][ug + j][d_c];                          \
                ch[j] = f2bf_rne(x);                                         \
                cl[j] = f2bf_rne(x - bf2f(ch[j]));                           \
            }                                                                \
            ushort4 chv = {ch[0], ch[1], ch[2], ch[3]};                      \
            ushort4 clv = {cl[0], cl[1], cl[2], cl[3]};                      \
            *(ushort4*)&thb[(size_t)d_c * TT + (TC0) + ug] = chv;            \
            *(ushort4*)&tlb[(size_t)d_c * TT + (TC0) + ug] = clv;            \
        }

        {
            int id0 = idsb[0]; if ((unsigned)id0 >= VOCABN) id0 = 0;
            float ec = emb[id0 * DD + dd];
#pragma unroll
            for (int u = 0; u < UU; ++u) {
                float en = 0.f;
                if (u + 1 < UU) {
                    int idn = idsb[u + 1]; if ((unsigned)idn >= VOCABN) idn = 0;
                    en = emb[idn * DD + dd];
                }
                PROD_TOKEN(0, u, ec)
                ec = en;
            }
        }
        __syncthreads();
        int sel = 0;
        for (int t0 = 0; t0 < TT; t0 += UU) {
            if (t0 + UU < TT) {
                const int s = sel ^ 1;
                int id0 = idsb[t0 + UU]; if ((unsigned)id0 >= VOCABN) id0 = 0;
                float ec = emb[id0 * DD + dd];
#pragma unroll
                for (int u = 0; u < UU; ++u) {
                    float en = 0.f;
                    if (u + 1 < UU) {
                        int tn = t0 + UU + u + 1;
                        if (tn > TT - 1) tn = TT - 1;
                        int idn = idsb[tn]; if ((unsigned)idn >= VOCABN) idn = 0;
                        en = emb[idn * DD + dd];
                    }
                    PROD_TOKEN(s, u, ec)
                    ec = en;
                }
            }
            // cvt previous chunk (consumer wrote hring[(t0/UU-1)&1] before
            // the last barrier)
            if (t0) CVT_CHUNK((t0 / UU - 1) & 1, t0 - UU)
            __syncthreads();
            sel ^= 1;
        }
        // epilogue: convert the final chunk (written before the last barrier)
        CVT_CHUNK(1, TT - UU)
#undef PROD_TOKEN
#undef CVT_CHUNK
        return;
    }

    // ---------------- consumer: R19-exact scan + pk_fma dots ----------------
    const int d = l & 31;
    const bool hi = l >= 32;
    const int ga = (hi ? 32 : 0) + d;
    const int gb = (hi ? 96 : 64) + d;
    floatx2 rkp[DD];
#pragma unroll
    for (int k = 0; k < DD; ++k)
        rkp[k] = (floatx2){rk[k * GG + ga], rk[k * GG + gb]};
    float* hb = hout + (size_t)b * TT * DD;

    float h = 0.0f, c = 0.0f;
    float hreg[UU];
    __syncthreads();   // matches producer prologue barrier
    int sel = 0;
    for (int t0 = 0; t0 < TT; t0 += UU) {
        // flush previous chunk's h first: stores retire under this chunk's
        // compute, so the chunk-end barrier's vmcnt(0) drain is free.
        if (t0 && !hi) {
#pragma unroll
            for (int u = 0; u < UU; ++u) hb[(size_t)(t0 - UU + u) * DD + d] = hreg[u];
        }
        float pa[UU], pb[UU];
#pragma unroll
        for (int u = 0; u < UU; ++u) {
            pa[u] = ring[sel][u][ga];
            pb[u] = ring[sel][u][gb];
        }
#pragma unroll
        for (int u = 0; u < UU; ++u) {
            floatx2 x0 = {pa[u], pb[u]};
            floatx2 x1 = {0.f, 0.f}, x2 = {0.f, 0.f}, x3 = {0.f, 0.f};
#pragma unroll
            for (int k = 0; k < DD; k += 4) {
                float h0 = readlane_f(h, k);
                float h1 = readlane_f(h, k + 1);
                float h2 = readlane_f(h, k + 2);
                float h3 = readlane_f(h, k + 3);
                x0 = fma2(h0, rkp[k],     x0);
                x1 = fma2(h1, rkp[k + 1], x1);
                x2 = fma2(h2, rkp[k + 2], x2);
                x3 = fma2(h3, rkp[k + 3], x3);
            }
            floatx2 zf = (x0 + x1) + (x2 + x3);
            float za = zf.x, zb = zf.y;
            float a = fsig(za);                       // sig(i) lo / sig(f) hi
            float zbm = hi ? zb : 2.0f * zb;
            float s2 = fsig(zbm);
            float bv = hi ? s2 : 2.0f * s2 - 1.0f;    // sig(o) hi / tanh(g) lo
            // lane<32 <-> lane+32 exchange via v_permlane32_swap_b32 (VALU).
            auto r1 = __builtin_amdgcn_permlane32_swap(
                __float_as_int(bv), __float_as_int(a), false, false);
            auto r2 = __builtin_amdgcn_permlane32_swap(
                __float_as_int(a), __float_as_int(bv), false, false);
            float fg = __int_as_float(r1[0]);
            float og = __int_as_float(r2[0]);
            c = fmaf(fg, c, a * bv);
            float tc = 2.0f * fsig(2.0f * c) - 1.0f;
            h = og * tc;
            hreg[u] = h;
            if (!hi) hring[sel][u][d] = h;   // h ring for producer-side cvt
        }
        __syncthreads();
        sel ^= 1;
    }
    if (!hi) {
#pragma unroll
        for (int u = 0; u < UU; ++u) hb[(size_t)(TT - UU + u) * DD + d] = hreg[u];
    }
}

// ---------------------------------------------------------------------------
// Kernel 3: attention — R27: R25/R26 math (4 q-tiles/wave, verified) + two
// stall fixes (1 wave/SIMD has zero TLP, so every latency is exposed):
//  (a) 2-deep K/V register prefetch: {cur,next,next2} sets (+32 VGPR);
//      load->use distance = 2 iteration bodies (~1100 cyc) > L3/HBM latency.
//  (b) epilogue via per-wave LDS transpose tile ([64][34] f32, <=2-way bank):
//      coalesced 16B short8 stores (8/lane) instead of 64 scattered 2B
//      stores/lane (R26's regression). Identical bytes -> absmax unchanged.
// ---------------------------------------------------------------------------
__global__ __launch_bounds__(256, 1) void k_attn(const u16* __restrict__ hh,
                                                 const u16* __restrict__ hl,
                                                 const u16* __restrict__ th,
                                                 const u16* __restrict__ tl,
                                                 u16* __restrict__ cth,
                                                 u16* __restrict__ ctl) {
    __shared__ u16 plds[4][4][2][16 * 40];   // [wave][tile][dbuf][16x40]
    __shared__ float ctile[4][64][34];       // per-wave transpose staging
    const int tid = threadIdx.x;
    const int w = tid >> 6;
    const int l = tid & 63;
    const int m = l & 15;
    const int g = l >> 4;
    const int b = blockIdx.x & 63;              // XCD swizzle: XCD = b % 8
    const int qt = (blockIdx.x >> 6) * 4 + w;   // 64-row wave tile, 0..15
    const int q0 = qt * 64;
    const size_t rb = (size_t)b * TT * DD;
    const size_t tb = (size_t)b * DD * TT;

    const short8 Qh0 = *(const short8*)&hh[rb + (size_t)(q0 + m) * DD + g * 8];
    const short8 Ql0 = *(const short8*)&hl[rb + (size_t)(q0 + m) * DD + g * 8];
    const short8 Qh1 = *(const short8*)&hh[rb + (size_t)(q0 + 16 + m) * DD + g * 8];
    const short8 Ql1 = *(const short8*)&hl[rb + (size_t)(q0 + 16 + m) * DD + g * 8];
    const short8 Qh2 = *(const short8*)&hh[rb + (size_t)(q0 + 32 + m) * DD + g * 8];
    const short8 Ql2 = *(const short8*)&hl[rb + (size_t)(q0 + 32 + m) * DD + g * 8];
    const short8 Qh3 = *(const short8*)&hh[rb + (size_t)(q0 + 48 + m) * DD + g * 8];
    const short8 Ql3 = *(const short8*)&hl[rb + (size_t)(q0 + 48 + m) * DD + g * 8];
    short8 ONES;
#pragma unroll
    for (int j = 0; j < 8; ++j) ONES[j] = (short)0x3F80;

    floatx4 c0 = {0.f, 0.f, 0.f, 0.f}, c1 = {0.f, 0.f, 0.f, 0.f};
    floatx4 c2 = {0.f, 0.f, 0.f, 0.f}, c3 = {0.f, 0.f, 0.f, 0.f};
    floatx4 c4 = {0.f, 0.f, 0.f, 0.f}, c5 = {0.f, 0.f, 0.f, 0.f};
    floatx4 c6 = {0.f, 0.f, 0.f, 0.f}, c7 = {0.f, 0.f, 0.f, 0.f};
    floatx4 la0 = {0.f, 0.f, 0.f, 0.f}, la1 = {0.f, 0.f, 0.f, 0.f};
    floatx4 la2 = {0.f, 0.f, 0.f, 0.f}, la3 = {0.f, 0.f, 0.f, 0.f};

#define S_BLOCK(QH, QL, KH_A, KL_A, KH_B, KL_B, SA, SB)                       \
    SA = __builtin_amdgcn_mfma_f32_16x16x32_bf16(QH, KH_A, SA, 0, 0, 0);      \
    SA = __builtin_amdgcn_mfma_f32_16x16x32_bf16(QH, KL_A, SA, 0, 0, 0);      \
    SA = __builtin_amdgcn_mfma_f32_16x16x32_bf16(QL, KH_A, SA, 0, 0, 0);      \
    SB = __builtin_amdgcn_mfma_f32_16x16x32_bf16(QH, KH_B, SB, 0, 0, 0);      \
    SB = __builtin_amdgcn_mfma_f32_16x16x32_bf16(QH, KL_B, SB, 0, 0, 0);      \
    SB = __builtin_amdgcn_mfma_f32_16x16x32_bf16(QL, KH_B, SB, 0, 0, 0);

#define EXP_STORE(SA, SB, TILE, SLOT)                                         \
    {                                                                         \
        u16* lp = plds[w][TILE][SLOT];                                        \
        _Pragma("unroll")                                                     \
        for (int r = 0; r < 4; ++r) {                                         \
            lp[(g * 4 + r) * 40 + m]      = f2bf_rne(__expf(SA[r]));          \
            lp[(g * 4 + r) * 40 + 16 + m] = f2bf_rne(__expf(SB[r]));          \
        }                                                                     \
    }

    // ---- kp = 0: S + exp + write slot0 for all four tiles; no PV yet ----
    {
        short8 KhA = *(const short8*)&hh[rb + (size_t)(m) * DD + g * 8];
        short8 KlA = *(const short8*)&hl[rb + (size_t)(m) * DD + g * 8];
        short8 KhB = *(const short8*)&hh[rb + (size_t)(16 + m) * DD + g * 8];
        short8 KlB = *(const short8*)&hl[rb + (size_t)(16 + m) * DD + g * 8];
        floatx4 sA = {0.f, 0.f, 0.f, 0.f}, sB = {0.f, 0.f, 0.f, 0.f};
        floatx4 tA = {0.f, 0.f, 0.f, 0.f}, tB = {0.f, 0.f, 0.f, 0.f};
        floatx4 uA = {0.f, 0.f, 0.f, 0.f}, uB = {0.f, 0.f, 0.f, 0.f};
        floatx4 vA = {0.f, 0.f, 0.f, 0.f}, vB = {0.f, 0.f, 0.f, 0.f};
        S_BLOCK(Qh0, Ql0, KhA, KlA, KhB, KlB, sA, sB)
        S_BLOCK(Qh1, Ql1, KhA, KlA, KhB, KlB, tA, tB)
        S_BLOCK(Qh2, Ql2, KhA, KlA, KhB, KlB, uA, uB)
        S_BLOCK(Qh3, Ql3, KhA, KlA, KhB, KlB, vA, vB)
        EXP_STORE(sA, sB, 0, 0)
        EXP_STORE(tA, tB, 1, 0)
        EXP_STORE(uA, uB, 2, 0)
        EXP_STORE(vA, vB, 3, 0)
    }
    // 2-deep preload: V(0),V(1) and K(1),K(2) — shared by all four tiles
    short8 Vh0 = *(const short8*)&th[tb + (size_t)m * TT + g * 8];
    short8 Vl0 = *(const short8*)&tl[tb + (size_t)m * TT + g * 8];
    short8 Vh1 = *(const short8*)&th[tb + (size_t)(16 + m) * TT + g * 8];
    short8 Vl1 = *(const short8*)&tl[tb + (size_t)(16 + m) * TT + g * 8];
    short8 V2h0 = *(const short8*)&th[tb + (size_t)m * TT + 32 + g * 8];
    short8 V2l0 = *(const short8*)&tl[tb + (size_t)m * TT + 32 + g * 8];
    short8 V2h1 = *(const short8*)&th[tb + (size_t)(16 + m) * TT + 32 + g * 8];
    short8 V2l1 = *(const short8*)&tl[tb + (size_t)(16 + m) * TT + 32 + g * 8];
    short8 KhA = *(const short8*)&hh[rb + (size_t)(32 + m) * DD + g * 8];
    short8 KlA = *(const short8*)&hl[rb + (size_t)(32 + m) * DD + g * 8];
    short8 KhB = *(const short8*)&hh[rb + (size_t)(48 + m) * DD + g * 8];
    short8 KlB = *(const short8*)&hl[rb + (size_t)(48 + m) * DD + g * 8];
    short8 K2hA = *(const short8*)&hh[rb + (size_t)(64 + m) * DD + g * 8];
    short8 K2lA = *(const short8*)&hl[rb + (size_t)(64 + m) * DD + g * 8];
    short8 K2hB = *(const short8*)&hh[rb + (size_t)(80 + m) * DD + g * 8];
    short8 K2lB = *(const short8*)&hl[rb + (size_t)(80 + m) * DD + g * 8];

#pragma unroll 1
    for (int kp = 1; kp < 32; ++kp) {
        const int knK = (kp < 30) ? (kp + 2) * 32 : 0;   // K(kp+2), dummy tail
        const int knV = (kp < 31) ? (kp + 1) * 32 : 0;   // V(kp+1), dummy tail
        short8 nKhA = *(const short8*)&hh[rb + (size_t)(knK + m) * DD + g * 8];
        short8 nKlA = *(const short8*)&hl[rb + (size_t)(knK + m) * DD + g * 8];
        short8 nKhB = *(const short8*)&hh[rb + (size_t)(knK + 16 + m) * DD + g * 8];
        short8 nKlB = *(const short8*)&hl[rb + (size_t)(knK + 16 + m) * DD + g * 8];
        short8 nVh0 = *(const short8*)&th[tb + (size_t)m * TT + knV + g * 8];
        short8 nVl0 = *(const short8*)&tl[tb + (size_t)m * TT + knV + g * 8];
        short8 nVh1 = *(const short8*)&th[tb + (size_t)(16 + m) * TT + knV + g * 8];
        short8 nVl1 = *(const short8*)&tl[tb + (size_t)(16 + m) * TT + knV + g * 8];

        floatx4 sA = {0.f, 0.f, 0.f, 0.f}, sB = {0.f, 0.f, 0.f, 0.f};
        floatx4 tA = {0.f, 0.f, 0.f, 0.f}, tB = {0.f, 0.f, 0.f, 0.f};
        floatx4 uA = {0.f, 0.f, 0.f, 0.f}, uB = {0.f, 0.f, 0.f, 0.f};
        floatx4 vA = {0.f, 0.f, 0.f, 0.f}, vB = {0.f, 0.f, 0.f, 0.f};
        S_BLOCK(Qh0, Ql0, KhA, KlA, KhB, KlB, sA, sB)
        S_BLOCK(Qh1, Ql1, KhA, KlA, KhB, KlB, tA, tB)
        S_BLOCK(Qh2, Ql2, KhA, KlA, KhB, KlB, uA, uB)
        S_BLOCK(Qh3, Ql3, KhA, KlA, KhB, KlB, vA, vB)

        const int ps = (kp - 1) & 1;
        const short8 P0 = *(const short8*)&plds[w][0][ps][m * 40 + g * 8];
        const short8 P1 = *(const short8*)&plds[w][1][ps][m * 40 + g * 8];
        const short8 P2 = *(const short8*)&plds[w][2][ps][m * 40 + g * 8];
        const short8 P3 = *(const short8*)&plds[w][3][ps][m * 40 + g * 8];

        c0  = __builtin_amdgcn_mfma_f32_16x16x32_bf16(P0, Vh0, c0, 0, 0, 0);
        c0  = __builtin_amdgcn_mfma_f32_16x16x32_bf16(P0, Vl0, c0, 0, 0, 0);
        c1  = __builtin_amdgcn_mfma_f32_16x16x32_bf16(P0, Vh1, c1, 0, 0, 0);
        c1  = __builtin_amdgcn_mfma_f32_16x16x32_bf16(P0, Vl1, c1, 0, 0, 0);
        la0 = __builtin_amdgcn_mfma_f32_16x16x32_bf16(P0, ONES, la0, 0, 0, 0);
        c2  = __builtin_amdgcn_mfma_f32_16x16x32_bf16(P1, Vh0, c2, 0, 0, 0);
        c2  = __builtin_amdgcn_mfma_f32_16x16x32_bf16(P1, Vl0, c2, 0, 0, 0);
        c3  = __builtin_amdgcn_mfma_f32_16x16x32_bf16(P1, Vh1, c3, 0, 0, 0);
        c3  = __builtin_amdgcn_mfma_f32_16x16x32_bf16(P1, Vl1, c3, 0, 0, 0);
        la1 = __builtin_amdgcn_mfma_f32_16x16x32_bf16(P1, ONES, la1, 0, 0, 0);
        c4  = __builtin_amdgcn_mfma_f32_16x16x32_bf16(P2, Vh0, c4, 0, 0, 0);
        c4  = __builtin_amdgcn_mfma_f32_16x16x32_bf16(P2, Vl0, c4, 0, 0, 0);
        c5  = __builtin_amdgcn_mfma_f32_16x16x32_bf16(P2, Vh1, c5, 0, 0, 0);
        c5  = __builtin_amdgcn_mfma_f32_16x16x32_bf16(P2, Vl1, c5, 0, 0, 0);
        la2 = __builtin_amdgcn_mfma_f32_16x16x32_bf16(P2, ONES, la2, 0, 0, 0);
        c6  = __builtin_amdgcn_mfma_f32_16x16x32_bf16(P3, Vh0, c6, 0, 0, 0);
        c6  = __builtin_amdgcn_mfma_f32_16x16x32_bf16(P3, Vl0, c6, 0, 0, 0);
        c7  = __builtin_amdgcn_mfma_f32_16x16x32_bf16(P3, Vh1, c7, 0, 0, 0);
        c7  = __builtin_amdgcn_mfma_f32_16x16x32_bf16(P3, Vl1, c7, 0, 0, 0);
        la3 = __builtin_amdgcn_mfma_f32_16x16x32_bf16(P3, ONES, la3, 0, 0, 0);

        EXP_STORE(sA, sB, 0, kp & 1)
        EXP_STORE(tA, tB, 1, kp & 1)
        EXP_STORE(uA, uB, 2, kp & 1)
        EXP_STORE(vA, vB, 3, kp & 1)

        // rotate 2-deep queues
        KhA = K2hA; KlA = K2lA; KhB = K2hB; KlB = K2lB;
        K2hA = nKhA; K2lA = nKlA; K2hB = nKhB; K2lB = nKlB;
        Vh0 = V2h0; Vl0 = V2l0; Vh1 = V2h1; Vl1 = V2l1;
        V2h0 = nVh0; V2l0 = nVl0; V2h1 = nVh1; V2l1 = nVl1;
    }
    // epilogue: PV of kp=31 for all four tiles (Vh0 now = V(31))
    {
        const short8 P0 = *(const short8*)&plds[w][0][1][m * 40 + g * 8];
        const short8 P1 = *(const short8*)&plds[w][1][1][m * 40 + g * 8];
        const short8 P2 = *(const short8*)&plds[w][2][1][m * 40 + g * 8];
        const short8 P3 = *(const short8*)&plds[w][3][1][m * 40 + g * 8];
        c0  = __builtin_amdgcn_mfma_f32_16x16x32_bf16(P0, Vh0, c0, 0, 0, 0);
        c0  = __builtin_amdgcn_mfma_f32_16x16x32_bf16(P0, Vl0, c0, 0, 0, 0);
        c1  = __builtin_amdgcn_mfma_f32_16x16x32_bf16(P0, Vh1, c1, 0, 0, 0);
        c1  = __builtin_amdgcn_mfma_f32_16x16x32_bf16(P0, Vl1, c1, 0, 0, 0);
        la0 = __builtin_amdgcn_mfma_f32_16x16x32_bf16(P0, ONES, la0, 0, 0, 0);
        c2  = __builtin_amdgcn_mfma_f32_16x16x32_bf16(P1, Vh0, c2, 0, 0, 0);
        c2  = __builtin_amdgcn_mfma_f32_16x16x32_bf16(P1, Vl0, c2, 0, 0, 0);
        c3  = __builtin_amdgcn_mfma_f32_16x16x32_bf16(P1, Vh1, c3, 0, 0, 0);
        c3  = __builtin_amdgcn_mfma_f32_16x16x32_bf16(P1, Vl1, c3, 0, 0, 0);
        la1 = __builtin_amdgcn_mfma_f32_16x16x32_bf16(P1, ONES, la1, 0, 0, 0);
        c4  = __builtin_amdgcn_mfma_f32_16x16x32_bf16(P2, Vh0, c4, 0, 0, 0);
        c4  = __builtin_amdgcn_mfma_f32_16x16x32_bf16(P2, Vl0, c4, 0, 0, 0);
        c5  = __builtin_amdgcn_mfma_f32_16x16x32_bf16(P2, Vh1, c5, 0, 0, 0);
        c5  = __builtin_amdgcn_mfma_f32_16x16x32_bf16(P2, Vl1, c5, 0, 0, 0);
        la2 = __builtin_amdgcn_mfma_f32_16x16x32_bf16(P2, ONES, la2, 0, 0, 0);
        c6  = __builtin_amdgcn_mfma_f32_16x16x32_bf16(P3, Vh0, c6, 0, 0, 0);
        c6  = __builtin_amdgcn_mfma_f32_16x16x32_bf16(P3, Vl0, c6, 0, 0, 0);
        c7  = __builtin_amdgcn_mfma_f32_16x16x32_bf16(P3, Vh1, c7, 0, 0, 0);
        c7  = __builtin_amdgcn_mfma_f32_16x16x32_bf16(P3, Vl1, c7, 0, 0, 0);
        la3 = __builtin_amdgcn_mfma_f32_16x16x32_bf16(P3, ONES, la3, 0, 0, 0);
    }
#undef S_BLOCK
#undef EXP_STORE
    // R27 epilogue: stage C/l into per-wave LDS tile, then coalesced stores.
#pragma unroll
    for (int r = 0; r < 4; ++r) {
        float li0 = __builtin_amdgcn_rcpf(la0[r]);
        float li1 = __builtin_amdgcn_rcpf(la1[r]);
        float li2 = __builtin_amdgcn_rcpf(la2[r]);
        float li3 = __builtin_amdgcn_rcpf(la3[r]);
        ctile[w][g * 4 + r][m]            = c0[r] * li0;
        ctile[w][g * 4 + r][16 + m]       = c1[r] * li0;
        ctile[w][16 + g * 4 + r][m]       = c2[r] * li1;
        ctile[w][16 + g * 4 + r][16 + m]  = c3[r] * li1;
        ctile[w][32 + g * 4 + r][m]       = c4[r] * li2;
        ctile[w][32 + g * 4 + r][16 + m]  = c5[r] * li2;
        ctile[w][48 + g * 4 + r][m]       = c6[r] * li3;
        ctile[w][48 + g * 4 + r][16 + m]  = c7[r] * li3;
    }
    // per-wave only: same-wave LDS write->read, no barrier needed
    const int srow = l >> 3;          // 0..7
    const int tcol = (l & 7) * 8;     // 0,8,..,56
#pragma unroll
    for (int cblk = 0; cblk < 4; ++cblk) {
        const int dr = cblk * 8 + srow;
        short8 hvec, lvec;
#pragma unroll
        for (int j2 = 0; j2 < 8; ++j2) {
            float v = ctile[w][tcol + j2][dr];
            u16 hv = f2bf_rne(v);
            hvec[j2] = (short)hv;
            lvec[j2] = (short)f2bf_rne(v - bf2f(hv));
        }
        *(short8*)&cth[tb + (size_t)dr * TT + q0 + tcol] = hvec;
        *(short8*)&ctl[tb + (size_t)dr * TT + q0 + tcol] = lvec;
    }
}

// ---------------------------------------------------------------------------
// Kernel 4: ymlp — R26 MFMA version, unchanged (verified absmax 0.0).
// ---------------------------------------------------------------------------
__global__ __launch_bounds__(256) void k_ymlp(const u16* __restrict__ cth,
                                              const u16* __restrict__ ctl,
                                              const u16* __restrict__ th,
                                              const u16* __restrict__ tl,
                                              const float* __restrict__ W1,
                                              const float* __restrict__ b1,
                                              const float* __restrict__ W2,
                                              const float* __restrict__ b2,
                                              float* __restrict__ out) {
    const int b = blockIdx.x;
    const int tid = threadIdx.x;
    const int w = tid >> 6;
    const int l = tid & 63;
    const int m = l & 15;
    const int g = l >> 4;
    const size_t tb = (size_t)b * DD * TT;
    const int k0 = w * (TT / 4);

    floatx4 y00 = {0.f, 0.f, 0.f, 0.f}, y01 = {0.f, 0.f, 0.f, 0.f};
    floatx4 y10 = {0.f, 0.f, 0.f, 0.f}, y11 = {0.f, 0.f, 0.f, 0.f};
#pragma unroll 2
    for (int ks = 0; ks < TT / 4; ks += 32) {
        const size_t kk = (size_t)(k0 + ks + g * 8);
        short8 A0h = *(const short8*)&cth[tb + (size_t)m * TT + kk];
        short8 A0l = *(const short8*)&ctl[tb + (size_t)m * TT + kk];
        short8 A1h = *(const short8*)&cth[tb + (size_t)(16 + m) * TT + kk];
        short8 A1l = *(const short8*)&ctl[tb + (size_t)(16 + m) * TT + kk];
        short8 B0h = *(const short8*)&th[tb + (size_t)m * TT + kk];
        short8 B0l = *(const short8*)&tl[tb + (size_t)m * TT + kk];
        short8 B1h = *(const short8*)&th[tb + (size_t)(16 + m) * TT + kk];
        short8 B1l = *(const short8*)&tl[tb + (size_t)(16 + m) * TT + kk];
        y00 = __builtin_amdgcn_mfma_f32_16x16x32_bf16(A0h, B0h, y00, 0, 0, 0);
        y00 = __builtin_amdgcn_mfma_f32_16x16x32_bf16(A0h, B0l, y00, 0, 0, 0);
        y00 = __builtin_amdgcn_mfma_f32_16x16x32_bf16(A0l, B0h, y00, 0, 0, 0);
        y01 = __builtin_amdgcn_mfma_f32_16x16x32_bf16(A0h, B1h, y01, 0, 0, 0);
        y01 = __builtin_amdgcn_mfma_f32_16x16x32_bf16(A0h, B1l, y01, 0, 0, 0);
        y01 = __builtin_amdgcn_mfma_f32_16x16x32_bf16(A0l, B1h, y01, 0, 0, 0);
        y10 = __builtin_amdgcn_mfma_f32_16x16x32_bf16(A1h, B0h, y10, 0, 0, 0);
        y10 = __builtin_amdgcn_mfma_f32_16x16x32_bf16(A1h, B0l, y10, 0, 0, 0);
        y10 = __builtin_amdgcn_mfma_f32_16x16x32_bf16(A1l, B0h, y10, 0, 0, 0);
        y11 = __builtin_amdgcn_mfma_f32_16x16x32_bf16(A1h, B1h, y11, 0, 0, 0);
        y11 = __builtin_amdgcn_mfma_f32_16x16x32_bf16(A1h, B1l, y11, 0, 0, 0);
        y11 = __builtin_amdgcn_mfma_f32_16x16x32_bf16(A1l, B1h, y11, 0, 0, 0);
    }
    __shared__ float ysp[4][DD][DD];
#pragma unroll
    for (int r = 0; r < 4; ++r) {
        // C/D layout: col = l&15, row = (l>>4)*4 + r
        ysp[w][g * 4 + r][m]           = y00[r];
        ysp[w][g * 4 + r][16 + m]      = y01[r];
        ysp[w][16 + g * 4 + r][m]      = y10[r];
        ysp[w][16 + g * 4 + r][16 + m] = y11[r];
    }
    __syncthreads();
    const int e = tid & 31;
    const int d4 = (tid >> 5) * 4;
    __shared__ float ys[DD][DD];
#pragma unroll
    for (int r = 0; r < 4; ++r)
        ys[d4 + r][e] = (ysp[0][d4 + r][e] + ysp[1][d4 + r][e])
                      + (ysp[2][d4 + r][e] + ysp[3][d4 + r][e]);
    __syncthreads();
    __shared__ float yr[DD][33];
#pragma unroll
    for (int r = 0; r < 4; ++r) {
        float v = b1[e];
#pragma unroll
        for (int ee = 0; ee < DD; ++ee) v += ys[d4 + r][ee] * W1[ee * DD + e];
        yr[d4 + r][e] = fmaxf(v, 0.0f);
    }
    __syncthreads();
    if (tid < DD) {
        float v = b2[0];
#pragma unroll
        for (int ee = 0; ee < DD; ++ee) v += yr[tid][ee] * W2[ee];
        out[b * DD + tid] = 1.0f / (1.0f + expf(-v));
    }
}

// ---------------------------------------------------------------------------
extern "C" void kernel_launch(void* const* d_in, const int* in_sizes, int n_in,
                              void* d_out, int out_size, void* d_ws, size_t ws_size,
                              hipStream_t stream) {
    const int* ids   = (const int*)d_in[0];
    const float* emb = (const float*)d_in[1];
    const float* kl  = (const float*)d_in[2];
    const float* rk  = (const float*)d_in[3];
    const float* bl  = (const float*)d_in[4];
    const float* W1  = (const float*)d_in[5];
    const float* b1  = (const float*)d_in[6];
    const float* W2  = (const float*)d_in[7];
    const float* b2  = (const float*)d_in[8];
    float* out = (float*)d_out;

    char* ws = (char*)d_ws;
    const size_t H_ELEMS = (size_t)BB * TT * DD;   // 2,097,152
    u16* hh   = (u16*)ws;
    u16* hl   = (u16*)(ws + H_ELEMS * 2);
    u16* th   = (u16*)(ws + H_ELEMS * 4);
    u16* tl   = (u16*)(ws + H_ELEMS * 6);
    float* h  = (float*)(ws + H_ELEMS * 8);
    u16* cth  = (u16*)(ws + H_ELEMS * 8 + H_ELEMS * 4);
    u16* ctl  = (u16*)(ws + H_ELEMS * 8 + H_ELEMS * 4 + H_ELEMS * 2);
    int* list = (int*)(ws + H_ELEMS * 8 + H_ELEMS * 8);

    k_lstm_scan<<<BB + 1, 128, 0, stream>>>(ids, emb, kl, bl, rk, h,
                                            hh, hl, th, tl, list, out + BB * DD);
    k_attn<<<BB * 4, 256, 0, stream>>>(hh, hl, th, tl, cth, ctl);
    k_ymlp<<<BB, 256, 0, stream>>>(cth, ctl, th, tl, W1, b1, W2, b2, out);
}